// Round 2
// baseline (1096.327 us; speedup 1.0000x reference)
//
#include <hip/hip_runtime.h>

typedef __bf16 bf16x8 __attribute__((ext_vector_type(8)));
typedef float  f32x4  __attribute__((ext_vector_type(4)));

#define GLOAD_LDS16(gp, lp) \
  __builtin_amdgcn_global_load_lds((const __attribute__((address_space(1))) void*)(gp), \
                                   (__attribute__((address_space(3))) void*)(lp), 16, 0, 0)

__device__ __forceinline__ unsigned short f2bf(float f) {
  unsigned u = __float_as_uint(f);
  u += 0x7fffu + ((u >> 16) & 1u);
  return (unsigned short)(u >> 16);
}
__device__ __forceinline__ float bf2f(unsigned short h) {
  return __uint_as_float(((unsigned)h) << 16);
}
__device__ __forceinline__ f32x4 splat4(float v) { f32x4 r = {v, v, v, v}; return r; }

// unpack 4 consecutive bf16 (packed in two uints) -> f32x4
__device__ __forceinline__ f32x4 up4(unsigned lo, unsigned hi) {
  f32x4 r;
  r[0] = __uint_as_float(lo << 16); r[1] = __uint_as_float(lo & 0xffff0000u);
  r[2] = __uint_as_float(hi << 16); r[3] = __uint_as_float(hi & 0xffff0000u);
  return r;
}
__device__ __forceinline__ unsigned pk2(float a, float b) {
  return (unsigned)f2bf(a) | ((unsigned)f2bf(b) << 16);
}

__device__ __forceinline__ void store_out(unsigned short* C, size_t idx, float v) {
  C[idx] = f2bf(v);
}
__device__ __forceinline__ void store_out(float* C, size_t idx, float v) {
  C[idx] = v;
}

// ---------------- RMSNorm (prenorm) #1 ----------------
__global__ __launch_bounds__(256) void rmsnorm1_kernel(
    const float* __restrict__ hid, const float* __restrict__ resin,
    const float* __restrict__ w, float* __restrict__ resout,
    unsigned short* __restrict__ hout)
{
  const int row = blockIdx.x, t = threadIdx.x;
  const size_t base = (size_t)row * 1024;
  float4 h = ((const float4*)(hid + base))[t];
  float4 r = ((const float4*)(resin + base))[t];
  float4 s; s.x = h.x + r.x; s.y = h.y + r.y; s.z = h.z + r.z; s.w = h.w + r.w;
  float ss = s.x*s.x + s.y*s.y + s.z*s.z + s.w*s.w;
  #pragma unroll
  for (int off = 32; off; off >>= 1) ss += __shfl_down(ss, off, 64);
  __shared__ float red[4];
  if ((t & 63) == 0) red[t >> 6] = ss;
  __syncthreads();
  float tot = red[0] + red[1] + red[2] + red[3];
  float sc = rsqrtf(tot * (1.0f/1024.0f) + 1e-5f);
  ((float4*)(resout + base))[t] = s;
  float4 wv = ((const float4*)w)[t];
  ushort4 o = make_ushort4(f2bf(s.x*sc*wv.x), f2bf(s.y*sc*wv.y),
                           f2bf(s.z*sc*wv.z), f2bf(s.w*sc*wv.w));
  ((ushort4*)(hout + base))[t] = o;
}

// ---------------- RMSNorm (prenorm) #2 ----------------
__global__ __launch_bounds__(256) void rmsnorm2_kernel(
    const unsigned short* __restrict__ mo, const float* __restrict__ res1,
    const float* __restrict__ w, float* __restrict__ res_out,
    unsigned short* __restrict__ h2)
{
  const int row = blockIdx.x, t = threadIdx.x;
  const size_t base = (size_t)row * 1024;
  float4 r = ((const float4*)(res1 + base))[t];
  ushort4 m = ((const ushort4*)(mo + base))[t];
  float4 s; s.x = r.x + bf2f(m.x); s.y = r.y + bf2f(m.y);
            s.z = r.z + bf2f(m.z); s.w = r.w + bf2f(m.w);
  float ss = s.x*s.x + s.y*s.y + s.z*s.z + s.w*s.w;
  #pragma unroll
  for (int off = 32; off; off >>= 1) ss += __shfl_down(ss, off, 64);
  __shared__ float red[4];
  if ((t & 63) == 0) red[t >> 6] = ss;
  __syncthreads();
  float tot = red[0] + red[1] + red[2] + red[3];
  float sc = rsqrtf(tot * (1.0f/1024.0f) + 1e-5f);
  ((float4*)(res_out + base))[t] = s;
  float4 wv = ((const float4*)w)[t];
  ((ushort4*)(h2 + base))[t] = make_ushort4(f2bf(s.x*sc*wv.x), f2bf(s.y*sc*wv.y),
                                            f2bf(s.z*sc*wv.z), f2bf(s.w*sc*wv.w));
}

// ---------------- fp32 -> bf16 weight cast with row padding ----------------
__global__ __launch_bounds__(256) void cast_w(
    const float* __restrict__ src, unsigned short* __restrict__ dst,
    int rows, int cols, int prows)
{
  size_t i4 = ((size_t)blockIdx.x * 256 + threadIdx.x) * 4;
  size_t total = (size_t)prows * cols;
  if (i4 >= total) return;
  int r = (int)(i4 / cols);
  ushort4 o;
  if (r < rows) {
    float4 v = *(const float4*)(src + i4);
    o = make_ushort4(f2bf(v.x), f2bf(v.y), f2bf(v.z), f2bf(v.w));
  } else {
    o = make_ushort4(0, 0, 0, 0);
  }
  *(ushort4*)(dst + i4) = o;
}

// ================= bf16 GEMM (NT), 256x256 tile, BK=64, 8-wave 8-phase =================
// A: M x K row-major, row stride lda. W: N x K row-major packed (ldw = K), N padded to 256.
// Stores predicated on gn < Nst. Grid: (Npad/256, M/256), 512 threads.
// LDS: 2 dbuf x {A,B} x 2 halves x (128 x 64 bf16 = 16 KB) = 128 KiB.
// Swizzle: linear gload_lds dest + inverse-swizzled global source; ds_read applies
// byte ^= ((row&7)<<4). Counted vmcnt(2) once per K-tile; raw s_barrier (no drain).
template <typename OutT>
__global__ __launch_bounds__(512) void gemm256(
    const unsigned short* __restrict__ A, const unsigned short* __restrict__ W,
    OutT* __restrict__ C, int K, int lda, int ldc, int Nst)
{
  __shared__ unsigned short As[2][2][8192];
  __shared__ unsigned short Bs[2][2][8192];

  // XCD-bijective block swizzle (m204)
  const int gx = gridDim.x, nwg = gx * (int)gridDim.y;
  int lin = blockIdx.y * gx + blockIdx.x;
  {
    const int q = nwg >> 3, r = nwg & 7, xcd = lin & 7, lo = lin >> 3;
    lin = (xcd < r ? xcd * (q + 1) : r * (q + 1) + (xcd - r) * q) + lo;
  }
  const int n0 = (lin % gx) << 8, m0 = (lin / gx) << 8;

  const int t = threadIdx.x, lane = t & 63, w = t >> 6;
  const int wr = w >> 2, wc = w & 3;          // wave tile: rows [wr*128), cols [wc*64)
  const int fr = lane & 15, fq = lane >> 4;
  const int l3 = lane >> 3;
  const int sc = ((lane & 7) ^ l3) << 3;      // pre-swizzled source col (shorts)
  const int sr = (w << 3) + l3;               // source row within 64-row block
  const int cswz = (fr & 7) << 3;             // read-side swizzle (shorts)
  const int brow0 = (wc & 1) << 6;            // B row base within half

  f32x4 acc[8][4];
  #pragma unroll
  for (int i = 0; i < 8; ++i)
    #pragma unroll
    for (int j = 0; j < 4; ++j) acc[i][j] = splat4(0.f);

  auto stageA = [&](int buf, int h, int kc) {
    const unsigned short* g = A + (size_t)(m0 + h * 128 + sr) * lda + kc + sc;
    GLOAD_LDS16(g,                    &As[buf][h][w << 9]);
    GLOAD_LDS16(g + (size_t)64 * lda, &As[buf][h][4096 + (w << 9)]);
  };
  auto stageB = [&](int buf, int h, int kc) {
    const unsigned short* g = W + (size_t)(n0 + h * 128 + sr) * (size_t)K + kc + sc;
    GLOAD_LDS16(g,                  &Bs[buf][h][w << 9]);
    GLOAD_LDS16(g + (size_t)64 * K, &Bs[buf][h][4096 + (w << 9)]);
  };

#define QUAD(CB, MG, NG)                                                        \
  do {                                                                          \
    const unsigned short* Ah = &As[(CB)][wr][0];                                \
    const unsigned short* Bh = &Bs[(CB)][wc >> 1][0];                           \
    bf16x8 af[4][2], bq[2][2];                                                  \
    _Pragma("unroll") for (int m2 = 0; m2 < 4; ++m2)                            \
      _Pragma("unroll") for (int ks = 0; ks < 2; ++ks)                          \
        af[m2][ks] = *(const bf16x8*)(Ah + ((MG)*64 + m2*16 + fr) * 64          \
                                        + ((ks*32 + fq*8) ^ cswz));             \
    _Pragma("unroll") for (int n2 = 0; n2 < 2; ++n2)                            \
      _Pragma("unroll") for (int ks = 0; ks < 2; ++ks)                          \
        bq[n2][ks] = *(const bf16x8*)(Bh + (brow0 + (NG)*32 + n2*16 + fr) * 64  \
                                        + ((ks*32 + fq*8) ^ cswz));             \
    asm volatile("s_waitcnt lgkmcnt(0)" ::: "memory");                          \
    __builtin_amdgcn_sched_barrier(0);                                          \
    __builtin_amdgcn_s_setprio(1);                                              \
    _Pragma("unroll") for (int ks = 0; ks < 2; ++ks)                            \
      _Pragma("unroll") for (int m2 = 0; m2 < 4; ++m2)                          \
        _Pragma("unroll") for (int n2 = 0; n2 < 2; ++n2)                        \
          acc[(MG)*4 + m2][(NG)*2 + n2] = __builtin_amdgcn_mfma_f32_16x16x32_bf16( \
              af[m2][ks], bq[n2][ks], acc[(MG)*4 + m2][(NG)*2 + n2], 0, 0, 0);  \
    __builtin_amdgcn_s_setprio(0);                                              \
  } while (0)

  // prologue: stage K-tile 0 into buf 0
  stageA(0, 0, 0); stageA(0, 1, 0);
  stageB(0, 0, 0); stageB(0, 1, 0);

  const int NKT = K >> 6;
  for (int kt = 0; kt < NKT; ++kt) {
    const int cb = kt & 1, nb = cb ^ 1;
    const bool pre = (kt + 1 < NKT);
    const int kc = (kt + 1) << 6;
    // phase 0: stage A-half0 of next tile, drain previous tile's 8 loads (keep 2)
    if (pre) {
      stageA(nb, 0, kc);
      asm volatile("s_waitcnt vmcnt(2)" ::: "memory");
    } else {
      asm volatile("s_waitcnt vmcnt(0)" ::: "memory");
    }
    __builtin_amdgcn_s_barrier();
    QUAD(cb, 0, 0);
    __builtin_amdgcn_s_barrier();
    // phase 1
    if (pre) stageA(nb, 1, kc);
    QUAD(cb, 1, 0);
    __builtin_amdgcn_s_barrier();
    // phase 2
    if (pre) stageB(nb, 0, kc);
    QUAD(cb, 0, 1);
    __builtin_amdgcn_s_barrier();
    // phase 3
    if (pre) stageB(nb, 1, kc);
    QUAD(cb, 1, 1);
    __builtin_amdgcn_s_barrier();
  }
#undef QUAD

  #pragma unroll
  for (int mi = 0; mi < 8; ++mi)
    #pragma unroll
    for (int ni = 0; ni < 4; ++ni)
      #pragma unroll
      for (int rr = 0; rr < 4; ++rr) {
        const int gm = m0 + wr * 128 + mi * 16 + fq * 4 + rr;
        const int gn = n0 + wc * 64 + ni * 16 + fr;
        if (gn < Nst) store_out(C, (size_t)gm * ldc + gn, acc[mi][ni][rr]);
      }
}

// ---------------- causal depthwise conv (K=4) + silu, dt precompute ----------------
__global__ __launch_bounds__(256) void conv_dt_kernel(
    const unsigned short* __restrict__ zx, const float* __restrict__ conv_w,
    const float* __restrict__ conv_b, const float* __restrict__ dt_bias,
    const float* __restrict__ A_log, unsigned short* __restrict__ conv_out,
    float2* __restrict__ dtda)
{
  size_t idx = (size_t)blockIdx.x * 256 + threadIdx.x;
  if (idx >= (size_t)8192 * 2336) return;
  int c = (int)(idx % 2336);
  int row = (int)(idx / 2336);
  int l = row & 4095;
  if (c < 2304) {
    float acc = conv_b[c];
    const float* wp = conv_w + c * 4;
    #pragma unroll
    for (int j = 0; j < 4; j++) {
      int ls = l - 3 + j;
      if (ls >= 0) acc += bf2f(zx[(size_t)(row - 3 + j) * 4480 + 2048 + c]) * wp[j];
    }
    float s = acc / (1.0f + expf(-acc));
    conv_out[(size_t)row * 2304 + c] = f2bf(s);
  } else {
    int h = c - 2304;
    float draw = bf2f(zx[(size_t)row * 4480 + 4352 + h]) + dt_bias[h];
    float sp = (draw > 20.0f) ? draw : log1pf(expf(draw));
    float Ah = -expf(A_log[h]);
    dtda[(size_t)row * 32 + h] = make_float2(sp, expf(sp * Ah));
  }
}

// ============ chunked selective scan via MFMA (state-space-dual form) ============
// Q=128 chunk, 32 chunks/seq. Tile id: c = bid&31, h = (bid>>5)&31, b = bid>>10.

// Kernel A: per-chunk local end state S_end = (X .* w)^T @ B, w_j = exp(laQ-la_j)*dt_j.
__global__ __launch_bounds__(256) void chunk_state_kernel(
    const unsigned short* __restrict__ convo, const float2* __restrict__ dtda,
    const float* __restrict__ A_log, unsigned short* __restrict__ Sg,
    float* __restrict__ Pend)
{
  __shared__ __align__(16) unsigned short bT[128 * 136];  // B^T: [n][j]
  __shared__ __align__(16) unsigned short xT[64 * 136];   // weighted X^T: [p][j]
  __shared__ float wsh[128];
  const int t = threadIdx.x, lane = t & 63, wv = t >> 6;
  const int c = blockIdx.x & 31, h = (blockIdx.x >> 5) & 31, b = (int)(blockIdx.x >> 10);
  const size_t r0 = (size_t)b * 4096 + (size_t)c * 128;

  if (wv == 0) {
    const float A = -expf(A_log[h]);
    const float s0 = dtda[(r0 + 2 * lane) * 32 + h].x;
    const float s1 = dtda[(r0 + 2 * lane + 1) * 32 + h].x;
    const float v1 = s1 * A;
    float ps = s0 * A + v1;                         // pair sum of log-decay
    #pragma unroll
    for (int off = 1; off < 64; off <<= 1) {
      float n = __shfl_up(ps, off, 64);
      if (lane >= off) ps += n;
    }
    const float laQ = __shfl(ps, 63, 64);
    wsh[2 * lane]     = expf(laQ - (ps - v1)) * s0;  // la[2l] = ps - v1
    wsh[2 * lane + 1] = expf(laQ - ps) * s1;         // la[2l+1] = ps
    if (lane == 63) Pend[blockIdx.x] = expf(laQ);
  }
  __syncthreads();

  // stage weighted X^T: xT[p][j] = X[j][p] * w[j]
  {
    int j = t >> 3;
    const int p0 = (t & 7) << 3;
    #pragma unroll
    for (int it = 0; it < 4; ++it, j += 32) {
      const uint4 v = *(const uint4*)(convo + (r0 + j) * 2304 + h * 64 + p0);
      const float w = wsh[j];
      const unsigned arr[4] = {v.x, v.y, v.z, v.w};
      #pragma unroll
      for (int e = 0; e < 8; ++e) {
        const unsigned short raw = (unsigned short)(arr[e >> 1] >> ((e & 1) * 16));
        xT[(p0 + e) * 136 + j] = f2bf(bf2f(raw) * w);
      }
    }
  }
  // stage B^T: bT[n][j] = B[j][n]
  {
    int j = t >> 4;
    const int n0 = (t & 15) << 3;
    #pragma unroll
    for (int it = 0; it < 8; ++it, j += 16) {
      const uint4 v = *(const uint4*)(convo + (r0 + j) * 2304 + 2048 + n0);
      const unsigned arr[4] = {v.x, v.y, v.z, v.w};
      #pragma unroll
      for (int e = 0; e < 8; ++e)
        bT[(n0 + e) * 136 + j] = (unsigned short)(arr[e >> 1] >> ((e & 1) * 16));
    }
  }
  __syncthreads();

  const int fr = lane & 15, fq = lane >> 4;
  const int wn = wv << 5;                 // wave owns n columns [wn, wn+32)
  f32x4 acc[4][2];
  #pragma unroll
  for (int i = 0; i < 4; ++i)
    #pragma unroll
    for (int j = 0; j < 2; ++j) acc[i][j] = splat4(0.f);

  #pragma unroll
  for (int k0 = 0; k0 < 128; k0 += 32) {
    bf16x8 af[4], bf[2];
    #pragma unroll
    for (int i = 0; i < 4; ++i)
      af[i] = *(const bf16x8*)(xT + (i * 16 + fr) * 136 + fq * 8 + k0);
    #pragma unroll
    for (int j = 0; j < 2; ++j)
      bf[j] = *(const bf16x8*)(bT + (wn + j * 16 + fr) * 136 + fq * 8 + k0);
    #pragma unroll
    for (int i = 0; i < 4; ++i)
      #pragma unroll
      for (int j = 0; j < 2; ++j)
        acc[i][j] = __builtin_amdgcn_mfma_f32_16x16x32_bf16(af[i], bf[j], acc[i][j], 0, 0, 0);
  }

  const size_t slot = (size_t)blockIdx.x * 8192;
  #pragma unroll
  for (int i = 0; i < 4; ++i)
    #pragma unroll
    for (int j = 0; j < 2; ++j)
      #pragma unroll
      for (int r = 0; r < 4; ++r)
        Sg[slot + (size_t)(i * 16 + fq * 4 + r) * 128 + wn + j * 16 + fr] = f2bf(acc[i][j][r]);
}

// Kernel combine: sequential over 32 chunks; in-place Send -> Sstart. Elementwise.
__global__ __launch_bounds__(256) void chunk_combine_kernel(
    unsigned short* __restrict__ S, const float* __restrict__ Pend)
{
  const int t = threadIdx.x;
  const int sl = blockIdx.x & 7, bh = blockIdx.x >> 3;
  const size_t e = (size_t)sl * 1024 + (size_t)t * 4;
  f32x4 run = splat4(0.f);
  for (int c = 0; c < 32; ++c) {
    const size_t addr = (size_t)(bh * 32 + c) * 8192 + e;
    const uint2 a = *(const uint2*)(S + addr);
    const float P = Pend[bh * 32 + c];
    *(uint2*)(S + addr) = make_uint2(pk2(run[0], run[1]), pk2(run[2], run[3]));
    const f32x4 av = up4(a.x, a.y);
    run = av + splat4(P) * run;
  }
}

// Kernel B: y = (G .* decay-mask) @ X + diag(exp(la_i)) * (C @ S_start^T),
// then fused gate: out = (y + D*x) * silu(z), written IN PLACE over convo's x cols.
__global__ __launch_bounds__(256, 2) void chunk_output_kernel(
    unsigned short* __restrict__ convo, const float2* __restrict__ dtda,
    const float* __restrict__ A_log, const unsigned short* __restrict__ Sg,
    const unsigned short* __restrict__ zx, const float* __restrict__ D_param)
{
  __shared__ __align__(16) unsigned short bm[128 * 136]; // B tile [j][n], then M [i][j]
  __shared__ __align__(16) unsigned short xT[64 * 136];  // X^T [p][j]
  __shared__ float la_s[128];
  __shared__ float dt_s[128];
  const int t = threadIdx.x, lane = t & 63, wv = t >> 6;
  const int c = blockIdx.x & 31, h = (blockIdx.x >> 5) & 31, b = (int)(blockIdx.x >> 10);
  const size_t r0 = (size_t)b * 4096 + (size_t)c * 128;

  if (wv == 0) {
    const float A = -expf(A_log[h]);
    const float s0 = dtda[(r0 + 2 * lane) * 32 + h].x;
    const float s1 = dtda[(r0 + 2 * lane + 1) * 32 + h].x;
    const float v1 = s1 * A;
    float ps = s0 * A + v1;
    #pragma unroll
    for (int off = 1; off < 64; off <<= 1) {
      float n = __shfl_up(ps, off, 64);
      if (lane >= off) ps += n;
    }
    la_s[2 * lane] = ps - v1;
    la_s[2 * lane + 1] = ps;
    dt_s[2 * lane] = s0;
    dt_s[2 * lane + 1] = s1;
  }

  // stage B rows direct (row-major, K=n contiguous)
  {
    int j = t >> 4;
    const int n0 = (t & 15) << 3;
    #pragma unroll
    for (int it = 0; it < 8; ++it, j += 16)
      *(uint4*)(bm + j * 136 + n0) = *(const uint4*)(convo + (r0 + j) * 2304 + 2048 + n0);
  }
  // stage X^T (unweighted)
  {
    int j = t >> 3;
    const int p0 = (t & 7) << 3;
    #pragma unroll
    for (int it = 0; it < 4; ++it, j += 32) {
      const uint4 v = *(const uint4*)(convo + (r0 + j) * 2304 + h * 64 + p0);
      const unsigned arr[4] = {v.x, v.y, v.z, v.w};
      #pragma unroll
      for (int e = 0; e < 8; ++e)
        xT[(p0 + e) * 136 + j] = (unsigned short)(arr[e >> 1] >> ((e & 1) * 16));
    }
  }
  __syncthreads();

  const int fr = lane & 15, fq = lane >> 4;
  const int wm = wv << 5;                 // wave owns output rows [wm, wm+32)
  const unsigned short* Cbase = convo + r0 * 2304 + 2176 + fq * 8;

  // G = C @ B^T  (K = n).  C A-frags straight from global (L1/L2 resident).
  f32x4 acc_g[2][8];
  #pragma unroll
  for (int mt = 0; mt < 2; ++mt)
    #pragma unroll
    for (int nt = 0; nt < 8; ++nt) acc_g[mt][nt] = splat4(0.f);
  #pragma unroll
  for (int k0 = 0; k0 < 128; k0 += 32) {
    bf16x8 af[2], bg[8];
    #pragma unroll
    for (int mt = 0; mt < 2; ++mt)
      af[mt] = *(const bf16x8*)(Cbase + (size_t)(wm + mt * 16 + fr) * 2304 + k0);
    #pragma unroll
    for (int nt = 0; nt < 8; ++nt)
      bg[nt] = *(const bf16x8*)(bm + (nt * 16 + fr) * 136 + fq * 8 + k0);
    #pragma unroll
    for (int mt = 0; mt < 2; ++mt)
      #pragma unroll
      for (int nt = 0; nt < 8; ++nt)
        acc_g[mt][nt] = __builtin_amdgcn_mfma_f32_16x16x32_bf16(af[mt], bg[nt], acc_g[mt][nt], 0, 0, 0);
  }
  __syncthreads();  // all waves done reading B before M overwrites bm

  // decay-mask: M[i][j] = G[i][j]*exp(la_i-la_j)*dt_j for j<=i else 0  (bf16, over bm)
  #pragma unroll
  for (int mt = 0; mt < 2; ++mt)
    #pragma unroll
    for (int r = 0; r < 4; ++r) {
      const int i = wm + mt * 16 + fq * 4 + r;
      const float lai = la_s[i];
      #pragma unroll
      for (int nt = 0; nt < 8; ++nt) {
        const int j = nt * 16 + fr;
        float v = 0.f;
        if (j <= i) v = acc_g[mt][nt][r] * expf(lai - la_s[j]) * dt_s[j];
        bm[i * 136 + j] = f2bf(v);
      }
    }

  // Y_inter = C @ S_start^T  (K = n); S frags direct from global
  const size_t slot = (size_t)blockIdx.x * 8192;
  f32x4 acc_y[2][4];
  #pragma unroll
  for (int mt = 0; mt < 2; ++mt)
    #pragma unroll
    for (int pt = 0; pt < 4; ++pt) acc_y[mt][pt] = splat4(0.f);
  #pragma unroll
  for (int k0 = 0; k0 < 128; k0 += 32) {
    bf16x8 af[2], bs[4];
    #pragma unroll
    for (int mt = 0; mt < 2; ++mt)
      af[mt] = *(const bf16x8*)(Cbase + (size_t)(wm + mt * 16 + fr) * 2304 + k0);
    #pragma unroll
    for (int pt = 0; pt < 4; ++pt)
      bs[pt] = *(const bf16x8*)(Sg + slot + (size_t)(pt * 16 + fr) * 128 + fq * 8 + k0);
    #pragma unroll
    for (int mt = 0; mt < 2; ++mt)
      #pragma unroll
      for (int pt = 0; pt < 4; ++pt)
        acc_y[mt][pt] = __builtin_amdgcn_mfma_f32_16x16x32_bf16(af[mt], bs[pt], acc_y[mt][pt], 0, 0, 0);
  }
  // scale inter-chunk term by exp(la_i)
  #pragma unroll
  for (int mt = 0; mt < 2; ++mt)
    #pragma unroll
    for (int r = 0; r < 4; ++r) {
      const float el = expf(la_s[wm + mt * 16 + fq * 4 + r]);
      #pragma unroll
      for (int pt = 0; pt < 4; ++pt) acc_y[mt][pt][r] *= el;
    }
  __syncthreads();

  // y += M @ X  (K = j); M rows are wave-private
  #pragma unroll
  for (int k0 = 0; k0 < 128; k0 += 32) {
    bf16x8 am[2], bx[4];
    #pragma unroll
    for (int mt = 0; mt < 2; ++mt)
      am[mt] = *(const bf16x8*)(bm + (wm + mt * 16 + fr) * 136 + fq * 8 + k0);
    #pragma unroll
    for (int pt = 0; pt < 4; ++pt)
      bx[pt] = *(const bf16x8*)(xT + (pt * 16 + fr) * 136 + fq * 8 + k0);
    #pragma unroll
    for (int mt = 0; mt < 2; ++mt)
      #pragma unroll
      for (int pt = 0; pt < 4; ++pt)
        acc_y[mt][pt] = __builtin_amdgcn_mfma_f32_16x16x32_bf16(am[mt], bx[pt], acc_y[mt][pt], 0, 0, 0);
  }

  // fused gate epilogue: out = (y + D*x) * silu(z), in place over convo x-cols
  const float D = D_param[h];
  #pragma unroll
  for (int mt = 0; mt < 2; ++mt)
    #pragma unroll
    for (int r = 0; r < 4; ++r) {
      const int i = wm + mt * 16 + fq * 4 + r;
      const size_t grow = r0 + i;
      #pragma unroll
      for (int pt = 0; pt < 4; ++pt) {
        const int p = pt * 16 + fr;
        const float x = bf2f(xT[p * 136 + i]);
        const float z = bf2f(zx[grow * 4480 + h * 64 + p]);
        const float sg = z / (1.0f + expf(-z));
        convo[grow * 2304 + h * 64 + p] = f2bf((acc_y[mt][pt][r] + D * x) * sg);
      }
    }
}

// ---------------- SwiGLU activation: g = silu(g) * u, in place ----------------
__global__ __launch_bounds__(256) void act_kernel(
    unsigned short* __restrict__ g, const unsigned short* __restrict__ u)
{
  size_t i4 = ((size_t)blockIdx.x * 256 + threadIdx.x) * 4;
  if (i4 >= (size_t)8192 * 4096) return;
  ushort4 gv = *(ushort4*)(g + i4);
  ushort4 uv = *(const ushort4*)(u + i4);
  float x, s, o[4];
  x = bf2f(gv.x); s = x / (1.0f + expf(-x)); o[0] = s * bf2f(uv.x);
  x = bf2f(gv.y); s = x / (1.0f + expf(-x)); o[1] = s * bf2f(uv.y);
  x = bf2f(gv.z); s = x / (1.0f + expf(-x)); o[2] = s * bf2f(uv.z);
  x = bf2f(gv.w); s = x / (1.0f + expf(-x)); o[3] = s * bf2f(uv.w);
  *(ushort4*)(g + i4) = make_ushort4(f2bf(o[0]), f2bf(o[1]), f2bf(o[2]), f2bf(o[3]));
}

// ---------------- workspace arena (bytes) ----------------
static constexpr size_t OFF_RES1 = 0;            // fp32 8192x1024 (live until rmsnorm2)
static constexpr size_t OFF_H1   = 33554432;     // bf16 8192x1024 (h1; then Sg 33.55MB; then mamba_out)
static constexpr size_t OFF_W    = 83886080;     // bf16 weight staging (also Pend during scan)
static constexpr size_t OFF_ZX   = 93061120;     // bf16 8192x4480   (zxbcdt, then g_out)
static constexpr size_t OFF_CONV = 166461440;    // bf16 8192x2304   (in_proj W staging -> conv_out -> gated y -> h2)
static constexpr size_t OFF_DTDA = 204210176;    // float2 8192x32 (dt, dA) = 2 MB
static constexpr size_t OFF_U    = 0;            // bf16 8192x4096   (overlaps dead res1/h1/Sg)

extern "C" void kernel_launch(void* const* d_in, const int* in_sizes, int n_in,
                              void* d_out, int out_size, void* d_ws, size_t ws_size,
                              hipStream_t stream) {
  const float* hid      = (const float*)d_in[0];
  const float* resid    = (const float*)d_in[1];
  const float* ssm_w    = (const float*)d_in[2];
  const float* mlp_w    = (const float*)d_in[3];
  const float* in_proj  = (const float*)d_in[4];
  const float* conv_w   = (const float*)d_in[5];
  const float* conv_b   = (const float*)d_in[6];
  const float* dt_bias  = (const float*)d_in[7];
  const float* A_log    = (const float*)d_in[8];
  const float* D_param  = (const float*)d_in[9];
  const float* out_proj = (const float*)d_in[10];
  const float* gate_w   = (const float*)d_in[11];
  const float* up_w     = (const float*)d_in[12];
  const float* down_w   = (const float*)d_in[13];
  float* out = (float*)d_out;                       // fp32 output: [h | res]
  char* ws = (char*)d_ws;

  float*          res1  = (float*)(ws + OFF_RES1);
  unsigned short* h1    = (unsigned short*)(ws + OFF_H1);   // h1 / Sg / mamba_out
  unsigned short* Wb    = (unsigned short*)(ws + OFF_W);
  unsigned short* zx    = (unsigned short*)(ws + OFF_ZX);
  unsigned short* convo = (unsigned short*)(ws + OFF_CONV);
  float2*         dtda  = (float2*)(ws + OFF_DTDA);
  unsigned short* ub    = (unsigned short*)(ws + OFF_U);
  unsigned short* Sg    = h1;                               // 2048 tiles x 8192 bf16 = 33.55 MB
  float*          Pend  = (float*)(ws + OFF_W);             // 8KB, Wb dead during scan
  unsigned short* WinP  = convo;                            // in_proj weights (4608x1024), convo dead here

  rmsnorm1_kernel<<<8192, 256, 0, stream>>>(hid, resid, ssm_w, res1, h1);
  // in_proj weights padded to 4608 rows (18 x 256) staged in dead convo region
  cast_w<<<4608, 256, 0, stream>>>(in_proj, WinP, 4384, 1024, 4608);
  gemm256<unsigned short><<<dim3(18, 32), 512, 0, stream>>>(h1, WinP, zx, 1024, 1024, 4480, 4480);
  conv_dt_kernel<<<74752, 256, 0, stream>>>(zx, conv_w, conv_b, dt_bias, A_log,
                                            convo, dtda);
  // chunked scan, matmul form: local states -> sequential combine -> outputs+gate
  chunk_state_kernel<<<2048, 256, 0, stream>>>(convo, dtda, A_log, Sg, Pend);
  chunk_combine_kernel<<<512, 256, 0, stream>>>(Sg, Pend);
  chunk_output_kernel<<<2048, 256, 0, stream>>>(convo, dtda, A_log, Sg, zx, D_param);
  cast_w<<<2048, 256, 0, stream>>>(out_proj, Wb, 1024, 2048, 1024);
  gemm256<unsigned short><<<dim3(4, 32), 512, 0, stream>>>(convo, Wb, h1, 2048, 2304, 1024, 1024);
  rmsnorm2_kernel<<<8192, 256, 0, stream>>>(h1, res1, mlp_w, out + 8388608, convo);
  cast_w<<<4096, 256, 0, stream>>>(gate_w, Wb, 4096, 1024, 4096);
  gemm256<unsigned short><<<dim3(16, 32), 512, 0, stream>>>(convo, Wb, zx, 1024, 1024, 4096, 4096);
  cast_w<<<4096, 256, 0, stream>>>(up_w, Wb, 4096, 1024, 4096);
  gemm256<unsigned short><<<dim3(16, 32), 512, 0, stream>>>(convo, Wb, ub, 1024, 1024, 4096, 4096);
  act_kernel<<<32768, 256, 0, stream>>>(zx, ub);
  cast_w<<<4096, 256, 0, stream>>>(down_w, Wb, 1024, 4096, 1024);
  gemm256<float><<<dim3(4, 32), 512, 0, stream>>>(zx, Wb, out, 4096, 4096, 1024, 1024);
}

// Round 3
// 928.855 us; speedup vs baseline: 1.1803x; 1.1803x over previous
//
#include <hip/hip_runtime.h>

typedef __bf16 bf16x8 __attribute__((ext_vector_type(8)));
typedef float  f32x4  __attribute__((ext_vector_type(4)));

#define GLOAD_LDS16(gp, lp) \
  __builtin_amdgcn_global_load_lds((const __attribute__((address_space(1))) void*)(gp), \
                                   (__attribute__((address_space(3))) void*)(lp), 16, 0, 0)

__device__ __forceinline__ unsigned short f2bf(float f) {
  unsigned u = __float_as_uint(f);
  u += 0x7fffu + ((u >> 16) & 1u);
  return (unsigned short)(u >> 16);
}
__device__ __forceinline__ float bf2f(unsigned short h) {
  return __uint_as_float(((unsigned)h) << 16);
}
__device__ __forceinline__ f32x4 splat4(float v) { f32x4 r = {v, v, v, v}; return r; }

// unpack 4 consecutive bf16 (packed in two uints) -> f32x4
__device__ __forceinline__ f32x4 up4(unsigned lo, unsigned hi) {
  f32x4 r;
  r[0] = __uint_as_float(lo << 16); r[1] = __uint_as_float(lo & 0xffff0000u);
  r[2] = __uint_as_float(hi << 16); r[3] = __uint_as_float(hi & 0xffff0000u);
  return r;
}
__device__ __forceinline__ unsigned pk2(float a, float b) {
  return (unsigned)f2bf(a) | ((unsigned)f2bf(b) << 16);
}

__device__ __forceinline__ void store_out(unsigned short* C, size_t idx, float v) {
  C[idx] = f2bf(v);
}
__device__ __forceinline__ void store_out(float* C, size_t idx, float v) {
  C[idx] = v;
}

// ---------------- RMSNorm (prenorm) #1 ----------------
__global__ __launch_bounds__(256) void rmsnorm1_kernel(
    const float* __restrict__ hid, const float* __restrict__ resin,
    const float* __restrict__ w, float* __restrict__ resout,
    unsigned short* __restrict__ hout)
{
  const int row = blockIdx.x, t = threadIdx.x;
  const size_t base = (size_t)row * 1024;
  float4 h = ((const float4*)(hid + base))[t];
  float4 r = ((const float4*)(resin + base))[t];
  float4 s; s.x = h.x + r.x; s.y = h.y + r.y; s.z = h.z + r.z; s.w = h.w + r.w;
  float ss = s.x*s.x + s.y*s.y + s.z*s.z + s.w*s.w;
  #pragma unroll
  for (int off = 32; off; off >>= 1) ss += __shfl_down(ss, off, 64);
  __shared__ float red[4];
  if ((t & 63) == 0) red[t >> 6] = ss;
  __syncthreads();
  float tot = red[0] + red[1] + red[2] + red[3];
  float sc = rsqrtf(tot * (1.0f/1024.0f) + 1e-5f);
  ((float4*)(resout + base))[t] = s;
  float4 wv = ((const float4*)w)[t];
  ushort4 o = make_ushort4(f2bf(s.x*sc*wv.x), f2bf(s.y*sc*wv.y),
                           f2bf(s.z*sc*wv.z), f2bf(s.w*sc*wv.w));
  ((ushort4*)(hout + base))[t] = o;
}

// ---------------- RMSNorm (prenorm) #2 ----------------
__global__ __launch_bounds__(256) void rmsnorm2_kernel(
    const unsigned short* __restrict__ mo, const float* __restrict__ res1,
    const float* __restrict__ w, float* __restrict__ res_out,
    unsigned short* __restrict__ h2)
{
  const int row = blockIdx.x, t = threadIdx.x;
  const size_t base = (size_t)row * 1024;
  float4 r = ((const float4*)(res1 + base))[t];
  ushort4 m = ((const ushort4*)(mo + base))[t];
  float4 s; s.x = r.x + bf2f(m.x); s.y = r.y + bf2f(m.y);
            s.z = r.z + bf2f(m.z); s.w = r.w + bf2f(m.w);
  float ss = s.x*s.x + s.y*s.y + s.z*s.z + s.w*s.w;
  #pragma unroll
  for (int off = 32; off; off >>= 1) ss += __shfl_down(ss, off, 64);
  __shared__ float red[4];
  if ((t & 63) == 0) red[t >> 6] = ss;
  __syncthreads();
  float tot = red[0] + red[1] + red[2] + red[3];
  float sc = rsqrtf(tot * (1.0f/1024.0f) + 1e-5f);
  ((float4*)(res_out + base))[t] = s;
  float4 wv = ((const float4*)w)[t];
  ((ushort4*)(h2 + base))[t] = make_ushort4(f2bf(s.x*sc*wv.x), f2bf(s.y*sc*wv.y),
                                            f2bf(s.z*sc*wv.z), f2bf(s.w*sc*wv.w));
}

// ---------------- fp32 -> bf16 weight cast with row padding ----------------
__global__ __launch_bounds__(256) void cast_w(
    const float* __restrict__ src, unsigned short* __restrict__ dst,
    int rows, int cols, int prows)
{
  size_t i4 = ((size_t)blockIdx.x * 256 + threadIdx.x) * 4;
  size_t total = (size_t)prows * cols;
  if (i4 >= total) return;
  int r = (int)(i4 / cols);
  ushort4 o;
  if (r < rows) {
    float4 v = *(const float4*)(src + i4);
    o = make_ushort4(f2bf(v.x), f2bf(v.y), f2bf(v.z), f2bf(v.w));
  } else {
    o = make_ushort4(0, 0, 0, 0);
  }
  *(ushort4*)(dst + i4) = o;
}

// ================= bf16 GEMM (NT), 256 x TN tile, BK=64, K-slice phases =================
// A: M x K row-major, stride lda. W: N x K row-major packed. Grid: (Npad/TN, M/256).
// 512 threads = 8 waves (2 M-rows x 4 N-cols), per-wave C = 128 x TN/4.
// Phases progress through K-slices of 32: every wave consumes the SAME staged piece
// in the same phase -> uniform 2-phase stage-to-consume lag, counted vmcnt (never 0
// in steady state). LDS pieces [rows][32] with granule XOR swizzle
// g ^= (row ^ row>>2)&3; inverse applied on per-lane global source (linear LDS dest).
template <typename OutT, int TN>
__global__ __launch_bounds__(512) void gemm256(
    const unsigned short* __restrict__ A, const unsigned short* __restrict__ W,
    OutT* __restrict__ C, int K, int lda, int ldc, int Nst)
{
  constexpr int NI = TN / 64;            // B 16-frags per wave (4 or 2)
  constexpr int WN = TN / 4;             // per-wave N width
  constexpr int SB = 2 + TN / 128;       // stage batch: vmem instrs per wave per phase
  __shared__ unsigned short As[2][2][8192];
  __shared__ unsigned short Bs[2][2][TN * 32];

  // XCD-bijective block swizzle (m204)
  const int gx = gridDim.x, nwg = gx * (int)gridDim.y;
  int lin = blockIdx.y * gx + blockIdx.x;
  {
    const int q = nwg >> 3, r = nwg & 7, xcd = lin & 7, lo = lin >> 3;
    lin = (xcd < r ? xcd * (q + 1) : r * (q + 1) + (xcd - r) * q) + lo;
  }
  const int n0 = (lin % gx) * TN, m0 = (lin / gx) << 8;

  const int t = threadIdx.x, lane = t & 63, w = t >> 6;
  const int wr = w >> 2, wc = w & 3;
  const int fr = lane & 15, fq = lane >> 4;
  const int gsw = ((fq ^ ((fr ^ (fr >> 2)) & 3)) << 3);  // read-side granule swizzle
  // stage source coords (per lane)
  const int srl = t >> 2;                                 // row within 128-row call
  const int sg  = (t & 3);                                // granule within row

  f32x4 acc[8][NI];
  #pragma unroll
  for (int i = 0; i < 8; ++i)
    #pragma unroll
    for (int j = 0; j < NI; ++j) acc[i][j] = splat4(0.f);

  auto stageA = [&](int buf, int ks, int kc) {
    #pragma unroll
    for (int h = 0; h < 2; ++h) {
      const int rl = h * 128 + srl;
      const int swz = (rl ^ (rl >> 2)) & 3;
      const unsigned short* g = A + (size_t)(m0 + rl) * lda + kc + ks * 32 + ((sg ^ swz) << 3);
      GLOAD_LDS16(g, &As[buf][ks][h * 4096 + (w << 9)]);
    }
  };
  auto stageB = [&](int buf, int ks, int kc) {
    #pragma unroll
    for (int h = 0; h < TN / 128; ++h) {
      const int rl = h * 128 + srl;
      const int swz = (rl ^ (rl >> 2)) & 3;
      const unsigned short* g = W + (size_t)(n0 + rl) * (size_t)K + kc + ks * 32 + ((sg ^ swz) << 3);
      GLOAD_LDS16(g, &Bs[buf][ks][h * 4096 + (w << 9)]);
    }
  };

  auto phase = [&](int cb, int ks) {
    bf16x8 af[8], bq[NI];
    #pragma unroll
    for (int mi = 0; mi < 8; ++mi) {
      const int R = wr * 128 + mi * 16 + fr;
      af[mi] = *(const bf16x8*)(&As[cb][ks][R * 32 + gsw]);
    }
    #pragma unroll
    for (int ni = 0; ni < NI; ++ni) {
      const int R = wc * WN + ni * 16 + fr;
      bq[ni] = *(const bf16x8*)(&Bs[cb][ks][R * 32 + gsw]);
    }
    __builtin_amdgcn_s_setprio(1);
    #pragma unroll
    for (int mi = 0; mi < 8; ++mi)
      #pragma unroll
      for (int ni = 0; ni < NI; ++ni)
        acc[mi][ni] = __builtin_amdgcn_mfma_f32_16x16x32_bf16(af[mi], bq[ni], acc[mi][ni], 0, 0, 0);
    __builtin_amdgcn_s_setprio(0);
  };

  // prologue: stage K-tile 0 (both K-slices) into buf 0
  stageA(0, 0, 0); stageB(0, 0, 0);
  stageA(0, 1, 0); stageB(0, 1, 0);

  const int NKT = K >> 6;
  for (int kt = 0; kt < NKT; ++kt) {
    const int cb = kt & 1, nb = cb ^ 1;
    const bool pre = (kt + 1 < NKT);
    const int kc = (kt + 1) << 6;
    // ---- phase ks=0: consume piece staged 2 phases ago
    if (pre) {
      stageA(nb, 0, kc); stageB(nb, 0, kc);
      asm volatile("s_waitcnt vmcnt(%0)" :: "n"(2 * SB) : "memory");
    } else {
      asm volatile("s_waitcnt vmcnt(%0)" :: "n"(SB) : "memory");
    }
    asm volatile("s_barrier" ::: "memory");
    phase(cb, 0);
    asm volatile("s_barrier" ::: "memory");
    // ---- phase ks=1
    if (pre) {
      stageA(nb, 1, kc); stageB(nb, 1, kc);
      asm volatile("s_waitcnt vmcnt(%0)" :: "n"(2 * SB) : "memory");
    } else {
      asm volatile("s_waitcnt vmcnt(0)" ::: "memory");
    }
    asm volatile("s_barrier" ::: "memory");
    phase(cb, 1);
    asm volatile("s_barrier" ::: "memory");
  }

  #pragma unroll
  for (int mi = 0; mi < 8; ++mi)
    #pragma unroll
    for (int ni = 0; ni < NI; ++ni)
      #pragma unroll
      for (int rr = 0; rr < 4; ++rr) {
        const int gm = m0 + wr * 128 + mi * 16 + fq * 4 + rr;
        const int gn = n0 + wc * WN + ni * 16 + fr;
        if (gn < Nst) store_out(C, (size_t)gm * ldc + gn, acc[mi][ni][rr]);
      }
}

// ---------------- causal depthwise conv (K=4) + silu, dt precompute ----------------
__global__ __launch_bounds__(256) void conv_dt_kernel(
    const unsigned short* __restrict__ zx, const float* __restrict__ conv_w,
    const float* __restrict__ conv_b, const float* __restrict__ dt_bias,
    const float* __restrict__ A_log, unsigned short* __restrict__ conv_out,
    float2* __restrict__ dtda)
{
  size_t idx = (size_t)blockIdx.x * 256 + threadIdx.x;
  if (idx >= (size_t)8192 * 2336) return;
  int c = (int)(idx % 2336);
  int row = (int)(idx / 2336);
  int l = row & 4095;
  if (c < 2304) {
    float acc = conv_b[c];
    const float* wp = conv_w + c * 4;
    #pragma unroll
    for (int j = 0; j < 4; j++) {
      int ls = l - 3 + j;
      if (ls >= 0) acc += bf2f(zx[(size_t)(row - 3 + j) * 4480 + 2048 + c]) * wp[j];
    }
    float s = acc / (1.0f + expf(-acc));
    conv_out[(size_t)row * 2304 + c] = f2bf(s);
  } else {
    int h = c - 2304;
    float draw = bf2f(zx[(size_t)row * 4480 + 4352 + h]) + dt_bias[h];
    float sp = (draw > 20.0f) ? draw : log1pf(expf(draw));
    float Ah = -expf(A_log[h]);
    dtda[(size_t)row * 32 + h] = make_float2(sp, expf(sp * Ah));
  }
}

// ============ chunked selective scan via MFMA (state-space-dual form) ============
// Q=128 chunk, 32 chunks/seq. Tile id: c = bid&31, h = (bid>>5)&31, b = bid>>10.

// Kernel A: per-chunk local end state S_end = (X .* w)^T @ B, w_j = exp(laQ-la_j)*dt_j.
__global__ __launch_bounds__(256) void chunk_state_kernel(
    const unsigned short* __restrict__ convo, const float2* __restrict__ dtda,
    const float* __restrict__ A_log, unsigned short* __restrict__ Sg,
    float* __restrict__ Pend)
{
  __shared__ __align__(16) unsigned short bT[128 * 136];  // B^T: [n][j]
  __shared__ __align__(16) unsigned short xT[64 * 136];   // weighted X^T: [p][j]
  __shared__ float wsh[128];
  const int t = threadIdx.x, lane = t & 63, wv = t >> 6;
  const int c = blockIdx.x & 31, h = (blockIdx.x >> 5) & 31, b = (int)(blockIdx.x >> 10);
  const size_t r0 = (size_t)b * 4096 + (size_t)c * 128;

  if (wv == 0) {
    const float A = -expf(A_log[h]);
    const float s0 = dtda[(r0 + 2 * lane) * 32 + h].x;
    const float s1 = dtda[(r0 + 2 * lane + 1) * 32 + h].x;
    const float v1 = s1 * A;
    float ps = s0 * A + v1;                         // pair sum of log-decay
    #pragma unroll
    for (int off = 1; off < 64; off <<= 1) {
      float n = __shfl_up(ps, off, 64);
      if (lane >= off) ps += n;
    }
    const float laQ = __shfl(ps, 63, 64);
    wsh[2 * lane]     = expf(laQ - (ps - v1)) * s0;  // la[2l] = ps - v1
    wsh[2 * lane + 1] = expf(laQ - ps) * s1;         // la[2l+1] = ps
    if (lane == 63) Pend[blockIdx.x] = expf(laQ);
  }
  __syncthreads();

  // stage weighted X^T: xT[p][j] = X[j][p] * w[j]
  {
    int j = t >> 3;
    const int p0 = (t & 7) << 3;
    #pragma unroll
    for (int it = 0; it < 4; ++it, j += 32) {
      const uint4 v = *(const uint4*)(convo + (r0 + j) * 2304 + h * 64 + p0);
      const float w = wsh[j];
      const unsigned arr[4] = {v.x, v.y, v.z, v.w};
      #pragma unroll
      for (int e = 0; e < 8; ++e) {
        const unsigned short raw = (unsigned short)(arr[e >> 1] >> ((e & 1) * 16));
        xT[(p0 + e) * 136 + j] = f2bf(bf2f(raw) * w);
      }
    }
  }
  // stage B^T: bT[n][j] = B[j][n]
  {
    int j = t >> 4;
    const int n0 = (t & 15) << 3;
    #pragma unroll
    for (int it = 0; it < 8; ++it, j += 16) {
      const uint4 v = *(const uint4*)(convo + (r0 + j) * 2304 + 2048 + n0);
      const unsigned arr[4] = {v.x, v.y, v.z, v.w};
      #pragma unroll
      for (int e = 0; e < 8; ++e)
        bT[(n0 + e) * 136 + j] = (unsigned short)(arr[e >> 1] >> ((e & 1) * 16));
    }
  }
  __syncthreads();

  const int fr = lane & 15, fq = lane >> 4;
  const int wn = wv << 5;                 // wave owns n columns [wn, wn+32)
  f32x4 acc[4][2];
  #pragma unroll
  for (int i = 0; i < 4; ++i)
    #pragma unroll
    for (int j = 0; j < 2; ++j) acc[i][j] = splat4(0.f);

  #pragma unroll
  for (int k0 = 0; k0 < 128; k0 += 32) {
    bf16x8 af[4], bf[2];
    #pragma unroll
    for (int i = 0; i < 4; ++i)
      af[i] = *(const bf16x8*)(xT + (i * 16 + fr) * 136 + fq * 8 + k0);
    #pragma unroll
    for (int j = 0; j < 2; ++j)
      bf[j] = *(const bf16x8*)(bT + (wn + j * 16 + fr) * 136 + fq * 8 + k0);
    #pragma unroll
    for (int i = 0; i < 4; ++i)
      #pragma unroll
      for (int j = 0; j < 2; ++j)
        acc[i][j] = __builtin_amdgcn_mfma_f32_16x16x32_bf16(af[i], bf[j], acc[i][j], 0, 0, 0);
  }

  const size_t slot = (size_t)blockIdx.x * 8192;
  #pragma unroll
  for (int i = 0; i < 4; ++i)
    #pragma unroll
    for (int j = 0; j < 2; ++j)
      #pragma unroll
      for (int r = 0; r < 4; ++r)
        Sg[slot + (size_t)(i * 16 + fq * 4 + r) * 128 + wn + j * 16 + fr] = f2bf(acc[i][j][r]);
}

// Kernel combine: sequential over 32 chunks; in-place Send -> Sstart. Elementwise.
__global__ __launch_bounds__(256) void chunk_combine_kernel(
    unsigned short* __restrict__ S, const float* __restrict__ Pend)
{
  const int t = threadIdx.x;
  const int sl = blockIdx.x & 7, bh = blockIdx.x >> 3;
  const size_t e = (size_t)sl * 1024 + (size_t)t * 4;
  f32x4 run = splat4(0.f);
  for (int c = 0; c < 32; ++c) {
    const size_t addr = (size_t)(bh * 32 + c) * 8192 + e;
    const uint2 a = *(const uint2*)(S + addr);
    const float P = Pend[bh * 32 + c];
    *(uint2*)(S + addr) = make_uint2(pk2(run[0], run[1]), pk2(run[2], run[3]));
    const f32x4 av = up4(a.x, a.y);
    run = av + splat4(P) * run;
  }
}

// Kernel B: y = (G .* decay-mask) @ X + diag(exp(la_i)) * (C @ S_start^T),
// then fused gate: out = (y + D*x) * silu(z), written IN PLACE over convo's x cols.
__global__ __launch_bounds__(256, 2) void chunk_output_kernel(
    unsigned short* __restrict__ convo, const float2* __restrict__ dtda,
    const float* __restrict__ A_log, const unsigned short* __restrict__ Sg,
    const unsigned short* __restrict__ zx, const float* __restrict__ D_param)
{
  __shared__ __align__(16) unsigned short bm[128 * 136]; // B tile [j][n], then M [i][j]
  __shared__ __align__(16) unsigned short xT[64 * 136];  // X^T [p][j]
  __shared__ float la_s[128];
  __shared__ float dt_s[128];
  const int t = threadIdx.x, lane = t & 63, wv = t >> 6;
  const int c = blockIdx.x & 31, h = (blockIdx.x >> 5) & 31, b = (int)(blockIdx.x >> 10);
  const size_t r0 = (size_t)b * 4096 + (size_t)c * 128;

  if (wv == 0) {
    const float A = -expf(A_log[h]);
    const float s0 = dtda[(r0 + 2 * lane) * 32 + h].x;
    const float s1 = dtda[(r0 + 2 * lane + 1) * 32 + h].x;
    const float v1 = s1 * A;
    float ps = s0 * A + v1;
    #pragma unroll
    for (int off = 1; off < 64; off <<= 1) {
      float n = __shfl_up(ps, off, 64);
      if (lane >= off) ps += n;
    }
    la_s[2 * lane] = ps - v1;
    la_s[2 * lane + 1] = ps;
    dt_s[2 * lane] = s0;
    dt_s[2 * lane + 1] = s1;
  }

  // stage B rows direct (row-major, K=n contiguous)
  {
    int j = t >> 4;
    const int n0 = (t & 15) << 3;
    #pragma unroll
    for (int it = 0; it < 8; ++it, j += 16)
      *(uint4*)(bm + j * 136 + n0) = *(const uint4*)(convo + (r0 + j) * 2304 + 2048 + n0);
  }
  // stage X^T (unweighted)
  {
    int j = t >> 3;
    const int p0 = (t & 7) << 3;
    #pragma unroll
    for (int it = 0; it < 4; ++it, j += 32) {
      const uint4 v = *(const uint4*)(convo + (r0 + j) * 2304 + h * 64 + p0);
      const unsigned arr[4] = {v.x, v.y, v.z, v.w};
      #pragma unroll
      for (int e = 0; e < 8; ++e)
        xT[(p0 + e) * 136 + j] = (unsigned short)(arr[e >> 1] >> ((e & 1) * 16));
    }
  }
  __syncthreads();

  const int fr = lane & 15, fq = lane >> 4;
  const int wm = wv << 5;                 // wave owns output rows [wm, wm+32)
  const unsigned short* Cbase = convo + r0 * 2304 + 2176 + fq * 8;

  // G = C @ B^T  (K = n).  C A-frags straight from global (L1/L2 resident).
  f32x4 acc_g[2][8];
  #pragma unroll
  for (int mt = 0; mt < 2; ++mt)
    #pragma unroll
    for (int nt = 0; nt < 8; ++nt) acc_g[mt][nt] = splat4(0.f);
  #pragma unroll
  for (int k0 = 0; k0 < 128; k0 += 32) {
    bf16x8 af[2], bg[8];
    #pragma unroll
    for (int mt = 0; mt < 2; ++mt)
      af[mt] = *(const bf16x8*)(Cbase + (size_t)(wm + mt * 16 + fr) * 2304 + k0);
    #pragma unroll
    for (int nt = 0; nt < 8; ++nt)
      bg[nt] = *(const bf16x8*)(bm + (nt * 16 + fr) * 136 + fq * 8 + k0);
    #pragma unroll
    for (int mt = 0; mt < 2; ++mt)
      #pragma unroll
      for (int nt = 0; nt < 8; ++nt)
        acc_g[mt][nt] = __builtin_amdgcn_mfma_f32_16x16x32_bf16(af[mt], bg[nt], acc_g[mt][nt], 0, 0, 0);
  }
  __syncthreads();  // all waves done reading B before M overwrites bm

  // decay-mask: M[i][j] = G[i][j]*exp(la_i-la_j)*dt_j for j<=i else 0  (bf16, over bm)
  #pragma unroll
  for (int mt = 0; mt < 2; ++mt)
    #pragma unroll
    for (int r = 0; r < 4; ++r) {
      const int i = wm + mt * 16 + fq * 4 + r;
      const float lai = la_s[i];
      #pragma unroll
      for (int nt = 0; nt < 8; ++nt) {
        const int j = nt * 16 + fr;
        float v = 0.f;
        if (j <= i) v = acc_g[mt][nt][r] * expf(lai - la_s[j]) * dt_s[j];
        bm[i * 136 + j] = f2bf(v);
      }
    }

  // Y_inter = C @ S_start^T  (K = n); S frags direct from global
  const size_t slot = (size_t)blockIdx.x * 8192;
  f32x4 acc_y[2][4];
  #pragma unroll
  for (int mt = 0; mt < 2; ++mt)
    #pragma unroll
    for (int pt = 0; pt < 4; ++pt) acc_y[mt][pt] = splat4(0.f);
  #pragma unroll
  for (int k0 = 0; k0 < 128; k0 += 32) {
    bf16x8 af[2], bs[4];
    #pragma unroll
    for (int mt = 0; mt < 2; ++mt)
      af[mt] = *(const bf16x8*)(Cbase + (size_t)(wm + mt * 16 + fr) * 2304 + k0);
    #pragma unroll
    for (int pt = 0; pt < 4; ++pt)
      bs[pt] = *(const bf16x8*)(Sg + slot + (size_t)(pt * 16 + fr) * 128 + fq * 8 + k0);
    #pragma unroll
    for (int mt = 0; mt < 2; ++mt)
      #pragma unroll
      for (int pt = 0; pt < 4; ++pt)
        acc_y[mt][pt] = __builtin_amdgcn_mfma_f32_16x16x32_bf16(af[mt], bs[pt], acc_y[mt][pt], 0, 0, 0);
  }
  // scale inter-chunk term by exp(la_i)
  #pragma unroll
  for (int mt = 0; mt < 2; ++mt)
    #pragma unroll
    for (int r = 0; r < 4; ++r) {
      const float el = expf(la_s[wm + mt * 16 + fq * 4 + r]);
      #pragma unroll
      for (int pt = 0; pt < 4; ++pt) acc_y[mt][pt][r] *= el;
    }
  __syncthreads();

  // y += M @ X  (K = j); M rows are wave-private
  #pragma unroll
  for (int k0 = 0; k0 < 128; k0 += 32) {
    bf16x8 am[2], bx[4];
    #pragma unroll
    for (int mt = 0; mt < 2; ++mt)
      am[mt] = *(const bf16x8*)(bm + (wm + mt * 16 + fr) * 136 + fq * 8 + k0);
    #pragma unroll
    for (int pt = 0; pt < 4; ++pt)
      bx[pt] = *(const bf16x8*)(xT + (pt * 16 + fr) * 136 + fq * 8 + k0);
    #pragma unroll
    for (int mt = 0; mt < 2; ++mt)
      #pragma unroll
      for (int pt = 0; pt < 4; ++pt)
        acc_y[mt][pt] = __builtin_amdgcn_mfma_f32_16x16x32_bf16(am[mt], bx[pt], acc_y[mt][pt], 0, 0, 0);
  }

  // fused gate epilogue: out = (y + D*x) * silu(z), in place over convo x-cols
  const float D = D_param[h];
  #pragma unroll
  for (int mt = 0; mt < 2; ++mt)
    #pragma unroll
    for (int r = 0; r < 4; ++r) {
      const int i = wm + mt * 16 + fq * 4 + r;
      const size_t grow = r0 + i;
      #pragma unroll
      for (int pt = 0; pt < 4; ++pt) {
        const int p = pt * 16 + fr;
        const float x = bf2f(xT[p * 136 + i]);
        const float z = bf2f(zx[grow * 4480 + h * 64 + p]);
        const float sg = z / (1.0f + expf(-z));
        convo[grow * 2304 + h * 64 + p] = f2bf((acc_y[mt][pt][r] + D * x) * sg);
      }
    }
}

// ---------------- SwiGLU activation: g = silu(g) * u, in place ----------------
__global__ __launch_bounds__(256) void act_kernel(
    unsigned short* __restrict__ g, const unsigned short* __restrict__ u)
{
  size_t i4 = ((size_t)blockIdx.x * 256 + threadIdx.x) * 4;
  if (i4 >= (size_t)8192 * 4096) return;
  ushort4 gv = *(ushort4*)(g + i4);
  ushort4 uv = *(const ushort4*)(u + i4);
  float x, s, o[4];
  x = bf2f(gv.x); s = x / (1.0f + expf(-x)); o[0] = s * bf2f(uv.x);
  x = bf2f(gv.y); s = x / (1.0f + expf(-x)); o[1] = s * bf2f(uv.y);
  x = bf2f(gv.z); s = x / (1.0f + expf(-x)); o[2] = s * bf2f(uv.z);
  x = bf2f(gv.w); s = x / (1.0f + expf(-x)); o[3] = s * bf2f(uv.w);
  *(ushort4*)(g + i4) = make_ushort4(f2bf(o[0]), f2bf(o[1]), f2bf(o[2]), f2bf(o[3]));
}

// ---------------- workspace arena (bytes) ----------------
static constexpr size_t OFF_RES1 = 0;            // fp32 8192x1024 (live until rmsnorm2)
static constexpr size_t OFF_H1   = 33554432;     // bf16 8192x1024 (h1; then Sg 33.55MB; then mamba_out)
static constexpr size_t OFF_W    = 83886080;     // bf16 weight staging (also Pend during scan)
static constexpr size_t OFF_ZX   = 93061120;     // bf16 8192x4480   (zxbcdt, then g_out)
static constexpr size_t OFF_CONV = 166461440;    // bf16 8192x2304   (in_proj W staging -> conv_out -> gated y -> h2)
static constexpr size_t OFF_DTDA = 204210176;    // float2 8192x32 (dt, dA) = 2 MB
static constexpr size_t OFF_U    = 0;            // bf16 8192x4096   (overlaps dead res1/h1/Sg)

extern "C" void kernel_launch(void* const* d_in, const int* in_sizes, int n_in,
                              void* d_out, int out_size, void* d_ws, size_t ws_size,
                              hipStream_t stream) {
  const float* hid      = (const float*)d_in[0];
  const float* resid    = (const float*)d_in[1];
  const float* ssm_w    = (const float*)d_in[2];
  const float* mlp_w    = (const float*)d_in[3];
  const float* in_proj  = (const float*)d_in[4];
  const float* conv_w   = (const float*)d_in[5];
  const float* conv_b   = (const float*)d_in[6];
  const float* dt_bias  = (const float*)d_in[7];
  const float* A_log    = (const float*)d_in[8];
  const float* D_param  = (const float*)d_in[9];
  const float* out_proj = (const float*)d_in[10];
  const float* gate_w   = (const float*)d_in[11];
  const float* up_w     = (const float*)d_in[12];
  const float* down_w   = (const float*)d_in[13];
  float* out = (float*)d_out;                       // fp32 output: [h | res]
  char* ws = (char*)d_ws;

  float*          res1  = (float*)(ws + OFF_RES1);
  unsigned short* h1    = (unsigned short*)(ws + OFF_H1);   // h1 / Sg / mamba_out
  unsigned short* Wb    = (unsigned short*)(ws + OFF_W);
  unsigned short* zx    = (unsigned short*)(ws + OFF_ZX);
  unsigned short* convo = (unsigned short*)(ws + OFF_CONV);
  float2*         dtda  = (float2*)(ws + OFF_DTDA);
  unsigned short* ub    = (unsigned short*)(ws + OFF_U);
  unsigned short* Sg    = h1;                               // 2048 tiles x 8192 bf16 = 33.55 MB
  float*          Pend  = (float*)(ws + OFF_W);             // 8KB, Wb dead during scan
  unsigned short* WinP  = convo;                            // in_proj weights (4608x1024), convo dead here

  rmsnorm1_kernel<<<8192, 256, 0, stream>>>(hid, resid, ssm_w, res1, h1);
  // in_proj weights padded to 4608 rows (18 x 256) staged in dead convo region
  cast_w<<<4608, 256, 0, stream>>>(in_proj, WinP, 4384, 1024, 4608);
  gemm256<unsigned short, 256><<<dim3(18, 32), 512, 0, stream>>>(h1, WinP, zx, 1024, 1024, 4480, 4480);
  conv_dt_kernel<<<74752, 256, 0, stream>>>(zx, conv_w, conv_b, dt_bias, A_log,
                                            convo, dtda);
  // chunked scan, matmul form: local states -> sequential combine -> outputs+gate
  chunk_state_kernel<<<2048, 256, 0, stream>>>(convo, dtda, A_log, Sg, Pend);
  chunk_combine_kernel<<<512, 256, 0, stream>>>(Sg, Pend);
  chunk_output_kernel<<<2048, 256, 0, stream>>>(convo, dtda, A_log, Sg, zx, D_param);
  cast_w<<<2048, 256, 0, stream>>>(out_proj, Wb, 1024, 2048, 1024);
  gemm256<unsigned short, 128><<<dim3(8, 32), 512, 0, stream>>>(convo, Wb, h1, 2048, 2304, 1024, 1024);
  rmsnorm2_kernel<<<8192, 256, 0, stream>>>(h1, res1, mlp_w, out + 8388608, convo);
  cast_w<<<4096, 256, 0, stream>>>(gate_w, Wb, 4096, 1024, 4096);
  gemm256<unsigned short, 256><<<dim3(16, 32), 512, 0, stream>>>(convo, Wb, zx, 1024, 1024, 4096, 4096);
  cast_w<<<4096, 256, 0, stream>>>(up_w, Wb, 4096, 1024, 4096);
  gemm256<unsigned short, 256><<<dim3(16, 32), 512, 0, stream>>>(convo, Wb, ub, 1024, 1024, 4096, 4096);
  act_kernel<<<32768, 256, 0, stream>>>(zx, ub);
  cast_w<<<4096, 256, 0, stream>>>(down_w, Wb, 1024, 4096, 1024);
  gemm256<float, 128><<<dim3(8, 32), 512, 0, stream>>>(zx, Wb, out, 4096, 4096, 1024, 1024);
}

// Round 5
// 877.531 us; speedup vs baseline: 1.2493x; 1.0585x over previous
//
#include <hip/hip_runtime.h>

typedef __bf16 bf16x8 __attribute__((ext_vector_type(8)));
typedef float  f32x4  __attribute__((ext_vector_type(4)));

#define GLOAD_LDS16(gp, lp) \
  __builtin_amdgcn_global_load_lds((const __attribute__((address_space(1))) void*)(gp), \
                                   (__attribute__((address_space(3))) void*)(lp), 16, 0, 0)

__device__ __forceinline__ unsigned short f2bf(float f) {
  unsigned u = __float_as_uint(f);
  u += 0x7fffu + ((u >> 16) & 1u);
  return (unsigned short)(u >> 16);
}
__device__ __forceinline__ float bf2f(unsigned short h) {
  return __uint_as_float(((unsigned)h) << 16);
}
__device__ __forceinline__ f32x4 splat4(float v) { f32x4 r = {v, v, v, v}; return r; }

// unpack 4 consecutive bf16 (packed in two uints) -> f32x4
__device__ __forceinline__ f32x4 up4(unsigned lo, unsigned hi) {
  f32x4 r;
  r[0] = __uint_as_float(lo << 16); r[1] = __uint_as_float(lo & 0xffff0000u);
  r[2] = __uint_as_float(hi << 16); r[3] = __uint_as_float(hi & 0xffff0000u);
  return r;
}
__device__ __forceinline__ unsigned pk2(float a, float b) {
  return (unsigned)f2bf(a) | ((unsigned)f2bf(b) << 16);
}

__device__ __forceinline__ void store_out(unsigned short* C, size_t idx, float v) {
  C[idx] = f2bf(v);
}
__device__ __forceinline__ void store_out(float* C, size_t idx, float v) {
  C[idx] = v;
}

// ---------------- RMSNorm (prenorm) #1 ----------------
__global__ __launch_bounds__(256) void rmsnorm1_kernel(
    const float* __restrict__ hid, const float* __restrict__ resin,
    const float* __restrict__ w, float* __restrict__ resout,
    unsigned short* __restrict__ hout)
{
  const int row = blockIdx.x, t = threadIdx.x;
  const size_t base = (size_t)row * 1024;
  float4 h = ((const float4*)(hid + base))[t];
  float4 r = ((const float4*)(resin + base))[t];
  float4 s; s.x = h.x + r.x; s.y = h.y + r.y; s.z = h.z + r.z; s.w = h.w + r.w;
  float ss = s.x*s.x + s.y*s.y + s.z*s.z + s.w*s.w;
  #pragma unroll
  for (int off = 32; off; off >>= 1) ss += __shfl_down(ss, off, 64);
  __shared__ float red[4];
  if ((t & 63) == 0) red[t >> 6] = ss;
  __syncthreads();
  float tot = red[0] + red[1] + red[2] + red[3];
  float sc = rsqrtf(tot * (1.0f/1024.0f) + 1e-5f);
  ((float4*)(resout + base))[t] = s;
  float4 wv = ((const float4*)w)[t];
  ushort4 o = make_ushort4(f2bf(s.x*sc*wv.x), f2bf(s.y*sc*wv.y),
                           f2bf(s.z*sc*wv.z), f2bf(s.w*sc*wv.w));
  ((ushort4*)(hout + base))[t] = o;
}

// ---------------- RMSNorm (prenorm) #2 ----------------
__global__ __launch_bounds__(256) void rmsnorm2_kernel(
    const unsigned short* __restrict__ mo, const float* __restrict__ res1,
    const float* __restrict__ w, float* __restrict__ res_out,
    unsigned short* __restrict__ h2)
{
  const int row = blockIdx.x, t = threadIdx.x;
  const size_t base = (size_t)row * 1024;
  float4 r = ((const float4*)(res1 + base))[t];
  ushort4 m = ((const ushort4*)(mo + base))[t];
  float4 s; s.x = r.x + bf2f(m.x); s.y = r.y + bf2f(m.y);
            s.z = r.z + bf2f(m.z); s.w = r.w + bf2f(m.w);
  float ss = s.x*s.x + s.y*s.y + s.z*s.z + s.w*s.w;
  #pragma unroll
  for (int off = 32; off; off >>= 1) ss += __shfl_down(ss, off, 64);
  __shared__ float red[4];
  if ((t & 63) == 0) red[t >> 6] = ss;
  __syncthreads();
  float tot = red[0] + red[1] + red[2] + red[3];
  float sc = rsqrtf(tot * (1.0f/1024.0f) + 1e-5f);
  ((float4*)(res_out + base))[t] = s;
  float4 wv = ((const float4*)w)[t];
  ((ushort4*)(h2 + base))[t] = make_ushort4(f2bf(s.x*sc*wv.x), f2bf(s.y*sc*wv.y),
                                            f2bf(s.z*sc*wv.z), f2bf(s.w*sc*wv.w));
}

// ---------------- fp32 -> bf16 weight cast with row padding ----------------
__global__ __launch_bounds__(256) void cast_w(
    const float* __restrict__ src, unsigned short* __restrict__ dst,
    int rows, int cols, int prows)
{
  size_t i4 = ((size_t)blockIdx.x * 256 + threadIdx.x) * 4;
  size_t total = (size_t)prows * cols;
  if (i4 >= total) return;
  int r = (int)(i4 / cols);
  ushort4 o;
  if (r < rows) {
    float4 v = *(const float4*)(src + i4);
    o = make_ushort4(f2bf(v.x), f2bf(v.y), f2bf(v.z), f2bf(v.w));
  } else {
    o = make_ushort4(0, 0, 0, 0);
  }
  *(ushort4*)(dst + i4) = o;
}

// ================= bf16 GEMM (NT), 256 x TN tile, BK=64, 4-phase quadrant sched =====
// A: M x K row-major (stride lda). W: N x K row-major packed. Grid (Npad/TN, M/256),
// 512 threads = 8 waves (2M x 4N), per-wave C = 128 x TN/4.
// Per K-tile: 4 phases = 4 C-quadrants (mh,nh) in order (0,0),(0,1),(1,1),(1,0);
// register retention -> ds reads 12/4/8/4 b128 per phase. Stages (2 gloads each):
// A0(T)@(T-2).P3, B0(T)+A1(T)@(T-1).P0, B1(T)@(T-1).P1 -> every LDS overwrite is
// >=1 barrier after that region's last read. ONE vmcnt(6) per K-tile at P0
// (3 half-tiles = 6 loads in flight), vmcnt(0) only on the last tile.
// Swizzle: 16B-granule g ^= (row&7); linear gload_lds dest (lane*16), inverse
// swizzle on per-lane global source; ds_read applies same XOR -> conflict-free.
// All register-array indices are macro-literal (rule #20: no runtime indexing).
template <typename OutT, int TN>
__global__ __launch_bounds__(512) void gemm256(
    const unsigned short* __restrict__ A, const unsigned short* __restrict__ W,
    OutT* __restrict__ C, int K, int lda, int ldc, int Nst)
{
  constexpr int NH = TN / 128;          // B half-tiles (2 or 1)
  constexpr int WN = TN / 4;            // per-wave N width (64 or 32)
  constexpr int QN = TN / 128;          // N-frags per quadrant (2 or 1)
  __shared__ __align__(16) unsigned short As[2][2][8192];
  __shared__ __align__(16) unsigned short Bs[2][NH][8192];

  // XCD-bijective block swizzle (m204)
  const int gx = gridDim.x, nwg = gx * (int)gridDim.y;
  int lin = blockIdx.y * gx + blockIdx.x;
  {
    const int q = nwg >> 3, r = nwg & 7, xcd = lin & 7, lo = lin >> 3;
    lin = (xcd < r ? xcd * (q + 1) : r * (q + 1) + (xcd - r) * q) + lo;
  }
  const int n0 = (lin % gx) * TN, m0 = (lin / gx) << 8;

  const int t = threadIdx.x, lane = t & 63, w = t >> 6;
  const int wr = w >> 2, wc = w & 3;
  const int fr = lane & 15, fq = lane >> 4;

  f32x4 acc[8][2 * QN];
  #pragma unroll
  for (int i = 0; i < 8; ++i)
    #pragma unroll
    for (int j = 0; j < 2 * QN; ++j) acc[i][j] = splat4(0.f);

  auto stA = [&](int buf, int h, int kc) {
    #pragma unroll
    for (int r2 = 0; r2 < 2; ++r2) {
      const int R = r2 * 64 + (t >> 3);
      const unsigned short* g =
          A + (size_t)(m0 + h * 128 + R) * lda + kc + (((t & 7) ^ (R & 7)) << 3);
      GLOAD_LDS16(g, &As[buf][h][r2 * 4096 + t * 8]);
    }
  };
  auto stB = [&](int buf, int h, int kc) {
    #pragma unroll
    for (int r2 = 0; r2 < 2; ++r2) {
      const int R = r2 * 64 + (t >> 3);
      const unsigned short* g =
          W + (size_t)(n0 + h * 128 + R) * (size_t)K + kc + (((t & 7) ^ (R & 7)) << 3);
      GLOAD_LDS16(g, &Bs[buf][h][r2 * 4096 + t * 8]);
    }
  };

  bf16x8 af[4][2], bqX[QN][2], bqY[QN][2];

#define G256_LDA(MH)                                                           \
  _Pragma("unroll") for (int mi = 0; mi < 4; ++mi)                             \
    _Pragma("unroll") for (int ks = 0; ks < 2; ++ks) {                         \
      const int R = (MH) * 64 + mi * 16 + fr;                                  \
      af[mi][ks] = *(const bf16x8*)(&As[cb][wr][R * 64 +                       \
                        ((((ks << 2) + fq) ^ (R & 7)) << 3)]);                 \
    }

#define G256_LDB(BQ, NHH)                                                      \
  _Pragma("unroll") for (int ni = 0; ni < QN; ++ni)                            \
    _Pragma("unroll") for (int ks = 0; ks < 2; ++ks) {                         \
      const int half = (NH == 2) ? (wc >> 1) : 0;                              \
      const int R = (NH == 2) ? ((wc & 1) * 64 + (NHH) * 32 + ni * 16 + fr)    \
                              : (wc * 32 + (NHH) * 16 + fr);                   \
      BQ[ni][ks] = *(const bf16x8*)(&Bs[cb][half][R * 64 +                     \
                        ((((ks << 2) + fq) ^ (R & 7)) << 3)]);                 \
    }

#define G256_WAITL                                                             \
  asm volatile("s_waitcnt lgkmcnt(0)" ::: "memory");                           \
  __builtin_amdgcn_sched_barrier(0);

#define G256_MQ(BQ, MH, NHH)                                                   \
  __builtin_amdgcn_s_setprio(1);                                               \
  _Pragma("unroll") for (int ks = 0; ks < 2; ++ks)                             \
    _Pragma("unroll") for (int mi = 0; mi < 4; ++mi)                           \
      _Pragma("unroll") for (int ni = 0; ni < QN; ++ni)                        \
        acc[(MH) * 4 + mi][(NHH) * QN + ni] =                                  \
            __builtin_amdgcn_mfma_f32_16x16x32_bf16(                           \
                af[mi][ks], BQ[ni][ks],                                        \
                acc[(MH) * 4 + mi][(NHH) * QN + ni], 0, 0, 0);                 \
  __builtin_amdgcn_s_setprio(0);

  const int NKT = K >> 6;
  // prologue: tile0 complete + A0(1); order matches steady-state issue order
  stA(0, 0, 0);
  stB(0, 0, 0);
  stA(0, 1, 0);
  if (NH > 1) stB(0, 1, 0);
  if (NKT > 1) stA(1, 0, 64);

  for (int kt = 0; kt < NKT; ++kt) {
    const int cb = kt & 1, nb = cb ^ 1;
    const int kc1 = (kt + 1) << 6, kc2 = (kt + 2) << 6;
    const bool p1 = (kt + 1 < NKT), p2 = (kt + 2 < NKT);
    // ---- P0: quadrant (0,0)
    if (p1) {
      stB(nb, 0, kc1); stA(nb, 1, kc1);
      asm volatile("s_waitcnt vmcnt(6)" ::: "memory");
    } else {
      asm volatile("s_waitcnt vmcnt(0)" ::: "memory");
    }
    __builtin_amdgcn_s_barrier();          // tile kt fully visible to all waves
    G256_LDA(0)
    G256_LDB(bqX, 0)
    G256_WAITL
    G256_MQ(bqX, 0, 0)
    __builtin_amdgcn_s_barrier();
    // ---- P1: quadrant (0,1)
    if (NH > 1 && p1) stB(nb, 1, kc1);
    G256_LDB(bqY, 1)
    G256_WAITL
    G256_MQ(bqY, 0, 1)
    __builtin_amdgcn_s_barrier();
    // ---- P2: quadrant (1,1)
    G256_LDA(1)
    G256_WAITL
    G256_MQ(bqY, 1, 1)
    __builtin_amdgcn_s_barrier();
    // ---- P3: quadrant (1,0)
    if (p2) stA(cb, 0, kc2);               // A-half0 of tile kt+2: last read at P0
    G256_LDB(bqX, 0)
    G256_WAITL
    G256_MQ(bqX, 1, 0)
    __builtin_amdgcn_s_barrier();
  }
#undef G256_LDA
#undef G256_LDB
#undef G256_WAITL
#undef G256_MQ

  #pragma unroll
  for (int mi = 0; mi < 8; ++mi)
    #pragma unroll
    for (int ci = 0; ci < 2 * QN; ++ci)
      #pragma unroll
      for (int rr = 0; rr < 4; ++rr) {
        const int gm = m0 + wr * 128 + mi * 16 + fq * 4 + rr;
        const int gn = n0 + wc * WN + ci * 16 + fr;
        if (gn < Nst) store_out(C, (size_t)gm * ldc + gn, acc[mi][ci][rr]);
      }
}

// ---------------- causal depthwise conv (K=4) + silu, dt precompute ----------------
__global__ __launch_bounds__(256) void conv_dt_kernel(
    const unsigned short* __restrict__ zx, const float* __restrict__ conv_w,
    const float* __restrict__ conv_b, const float* __restrict__ dt_bias,
    const float* __restrict__ A_log, unsigned short* __restrict__ conv_out,
    float2* __restrict__ dtda)
{
  size_t idx = (size_t)blockIdx.x * 256 + threadIdx.x;
  if (idx >= (size_t)8192 * 2336) return;
  int c = (int)(idx % 2336);
  int row = (int)(idx / 2336);
  int l = row & 4095;
  if (c < 2304) {
    float acc = conv_b[c];
    const float* wp = conv_w + c * 4;
    #pragma unroll
    for (int j = 0; j < 4; j++) {
      int ls = l - 3 + j;
      if (ls >= 0) acc += bf2f(zx[(size_t)(row - 3 + j) * 4480 + 2048 + c]) * wp[j];
    }
    float s = acc / (1.0f + expf(-acc));
    conv_out[(size_t)row * 2304 + c] = f2bf(s);
  } else {
    int h = c - 2304;
    float draw = bf2f(zx[(size_t)row * 4480 + 4352 + h]) + dt_bias[h];
    float sp = (draw > 20.0f) ? draw : log1pf(expf(draw));
    float Ah = -expf(A_log[h]);
    dtda[(size_t)row * 32 + h] = make_float2(sp, expf(sp * Ah));
  }
}

// ============ chunked selective scan via MFMA (state-space-dual form) ============
// Q=128 chunk, 32 chunks/seq. Tile id: c = bid&31, h = (bid>>5)&31, b = bid>>10.

// Kernel A: per-chunk local end state S_end = (X .* w)^T @ B, w_j = exp(laQ-la_j)*dt_j.
__global__ __launch_bounds__(256) void chunk_state_kernel(
    const unsigned short* __restrict__ convo, const float2* __restrict__ dtda,
    const float* __restrict__ A_log, unsigned short* __restrict__ Sg,
    float* __restrict__ Pend)
{
  __shared__ __align__(16) unsigned short bT[128 * 136];  // B^T: [n][j]
  __shared__ __align__(16) unsigned short xT[64 * 136];   // weighted X^T: [p][j]
  __shared__ float wsh[128];
  const int t = threadIdx.x, lane = t & 63, wv = t >> 6;
  const int c = blockIdx.x & 31, h = (blockIdx.x >> 5) & 31, b = (int)(blockIdx.x >> 10);
  const size_t r0 = (size_t)b * 4096 + (size_t)c * 128;

  if (wv == 0) {
    const float A = -expf(A_log[h]);
    const float s0 = dtda[(r0 + 2 * lane) * 32 + h].x;
    const float s1 = dtda[(r0 + 2 * lane + 1) * 32 + h].x;
    const float v1 = s1 * A;
    float ps = s0 * A + v1;                         // pair sum of log-decay
    #pragma unroll
    for (int off = 1; off < 64; off <<= 1) {
      float n = __shfl_up(ps, off, 64);
      if (lane >= off) ps += n;
    }
    const float laQ = __shfl(ps, 63, 64);
    wsh[2 * lane]     = expf(laQ - (ps - v1)) * s0;  // la[2l] = ps - v1
    wsh[2 * lane + 1] = expf(laQ - ps) * s1;         // la[2l+1] = ps
    if (lane == 63) Pend[blockIdx.x] = expf(laQ);
  }
  __syncthreads();

  // stage weighted X^T: xT[p][j] = X[j][p] * w[j]
  {
    int j = t >> 3;
    const int p0 = (t & 7) << 3;
    #pragma unroll
    for (int it = 0; it < 4; ++it, j += 32) {
      const uint4 v = *(const uint4*)(convo + (r0 + j) * 2304 + h * 64 + p0);
      const float w = wsh[j];
      const unsigned arr[4] = {v.x, v.y, v.z, v.w};
      #pragma unroll
      for (int e = 0; e < 8; ++e) {
        const unsigned short raw = (unsigned short)(arr[e >> 1] >> ((e & 1) * 16));
        xT[(p0 + e) * 136 + j] = f2bf(bf2f(raw) * w);
      }
    }
  }
  // stage B^T: bT[n][j] = B[j][n]
  {
    int j = t >> 4;
    const int n0 = (t & 15) << 3;
    #pragma unroll
    for (int it = 0; it < 8; ++it, j += 16) {
      const uint4 v = *(const uint4*)(convo + (r0 + j) * 2304 + 2048 + n0);
      const unsigned arr[4] = {v.x, v.y, v.z, v.w};
      #pragma unroll
      for (int e = 0; e < 8; ++e)
        bT[(n0 + e) * 136 + j] = (unsigned short)(arr[e >> 1] >> ((e & 1) * 16));
    }
  }
  __syncthreads();

  const int fr = lane & 15, fq = lane >> 4;
  const int wn = wv << 5;                 // wave owns n columns [wn, wn+32)
  f32x4 acc[4][2];
  #pragma unroll
  for (int i = 0; i < 4; ++i)
    #pragma unroll
    for (int j = 0; j < 2; ++j) acc[i][j] = splat4(0.f);

  #pragma unroll
  for (int k0 = 0; k0 < 128; k0 += 32) {
    bf16x8 af[4], bf[2];
    #pragma unroll
    for (int i = 0; i < 4; ++i)
      af[i] = *(const bf16x8*)(xT + (i * 16 + fr) * 136 + fq * 8 + k0);
    #pragma unroll
    for (int j = 0; j < 2; ++j)
      bf[j] = *(const bf16x8*)(bT + (wn + j * 16 + fr) * 136 + fq * 8 + k0);
    #pragma unroll
    for (int i = 0; i < 4; ++i)
      #pragma unroll
      for (int j = 0; j < 2; ++j)
        acc[i][j] = __builtin_amdgcn_mfma_f32_16x16x32_bf16(af[i], bf[j], acc[i][j], 0, 0, 0);
  }

  const size_t slot = (size_t)blockIdx.x * 8192;
  #pragma unroll
  for (int i = 0; i < 4; ++i)
    #pragma unroll
    for (int j = 0; j < 2; ++j)
      #pragma unroll
      for (int r = 0; r < 4; ++r)
        Sg[slot + (size_t)(i * 16 + fq * 4 + r) * 128 + wn + j * 16 + fr] = f2bf(acc[i][j][r]);
}

// Kernel combine: sequential over 32 chunks; in-place Send -> Sstart. Elementwise.
__global__ __launch_bounds__(256) void chunk_combine_kernel(
    unsigned short* __restrict__ S, const float* __restrict__ Pend)
{
  const int t = threadIdx.x;
  const int sl = blockIdx.x & 7, bh = blockIdx.x >> 3;
  const size_t e = (size_t)sl * 1024 + (size_t)t * 4;
  f32x4 run = splat4(0.f);
  for (int c = 0; c < 32; ++c) {
    const size_t addr = (size_t)(bh * 32 + c) * 8192 + e;
    const uint2 a = *(const uint2*)(S + addr);
    const float P = Pend[bh * 32 + c];
    *(uint2*)(S + addr) = make_uint2(pk2(run[0], run[1]), pk2(run[2], run[3]));
    const f32x4 av = up4(a.x, a.y);
    run = av + splat4(P) * run;
  }
}

// Kernel B: y = (G .* decay-mask) @ X + diag(exp(la_i)) * (C @ S_start^T),
// then fused gate: out = (y + D*x) * silu(z), written IN PLACE over convo's x cols.
__global__ __launch_bounds__(256, 2) void chunk_output_kernel(
    unsigned short* __restrict__ convo, const float2* __restrict__ dtda,
    const float* __restrict__ A_log, const unsigned short* __restrict__ Sg,
    const unsigned short* __restrict__ zx, const float* __restrict__ D_param)
{
  __shared__ __align__(16) unsigned short bm[128 * 136]; // B tile [j][n], then M [i][j]
  __shared__ __align__(16) unsigned short xT[64 * 136];  // X^T [p][j]
  __shared__ float la_s[128];
  __shared__ float dt_s[128];
  const int t = threadIdx.x, lane = t & 63, wv = t >> 6;
  const int c = blockIdx.x & 31, h = (blockIdx.x >> 5) & 31, b = (int)(blockIdx.x >> 10);
  const size_t r0 = (size_t)b * 4096 + (size_t)c * 128;

  if (wv == 0) {
    const float A = -expf(A_log[h]);
    const float s0 = dtda[(r0 + 2 * lane) * 32 + h].x;
    const float s1 = dtda[(r0 + 2 * lane + 1) * 32 + h].x;
    const float v1 = s1 * A;
    float ps = s0 * A + v1;
    #pragma unroll
    for (int off = 1; off < 64; off <<= 1) {
      float n = __shfl_up(ps, off, 64);
      if (lane >= off) ps += n;
    }
    la_s[2 * lane] = ps - v1;
    la_s[2 * lane + 1] = ps;
    dt_s[2 * lane] = s0;
    dt_s[2 * lane + 1] = s1;
  }

  // stage B rows direct (row-major, K=n contiguous)
  {
    int j = t >> 4;
    const int n0 = (t & 15) << 3;
    #pragma unroll
    for (int it = 0; it < 8; ++it, j += 16)
      *(uint4*)(bm + j * 136 + n0) = *(const uint4*)(convo + (r0 + j) * 2304 + 2048 + n0);
  }
  // stage X^T (unweighted)
  {
    int j = t >> 3;
    const int p0 = (t & 7) << 3;
    #pragma unroll
    for (int it = 0; it < 4; ++it, j += 32) {
      const uint4 v = *(const uint4*)(convo + (r0 + j) * 2304 + h * 64 + p0);
      const unsigned arr[4] = {v.x, v.y, v.z, v.w};
      #pragma unroll
      for (int e = 0; e < 8; ++e)
        xT[(p0 + e) * 136 + j] = (unsigned short)(arr[e >> 1] >> ((e & 1) * 16));
    }
  }
  __syncthreads();

  const int fr = lane & 15, fq = lane >> 4;
  const int wm = wv << 5;                 // wave owns output rows [wm, wm+32)
  const unsigned short* Cbase = convo + r0 * 2304 + 2176 + fq * 8;

  // G = C @ B^T  (K = n).  C A-frags straight from global (L1/L2 resident).
  f32x4 acc_g[2][8];
  #pragma unroll
  for (int mt = 0; mt < 2; ++mt)
    #pragma unroll
    for (int nt = 0; nt < 8; ++nt) acc_g[mt][nt] = splat4(0.f);
  #pragma unroll
  for (int k0 = 0; k0 < 128; k0 += 32) {
    bf16x8 af[2], bg[8];
    #pragma unroll
    for (int mt = 0; mt < 2; ++mt)
      af[mt] = *(const bf16x8*)(Cbase + (size_t)(wm + mt * 16 + fr) * 2304 + k0);
    #pragma unroll
    for (int nt = 0; nt < 8; ++nt)
      bg[nt] = *(const bf16x8*)(bm + (nt * 16 + fr) * 136 + fq * 8 + k0);
    #pragma unroll
    for (int mt = 0; mt < 2; ++mt)
      #pragma unroll
      for (int nt = 0; nt < 8; ++nt)
        acc_g[mt][nt] = __builtin_amdgcn_mfma_f32_16x16x32_bf16(af[mt], bg[nt], acc_g[mt][nt], 0, 0, 0);
  }
  __syncthreads();  // all waves done reading B before M overwrites bm

  // decay-mask: M[i][j] = G[i][j]*exp(la_i-la_j)*dt_j for j<=i else 0  (bf16, over bm)
  #pragma unroll
  for (int mt = 0; mt < 2; ++mt)
    #pragma unroll
    for (int r = 0; r < 4; ++r) {
      const int i = wm + mt * 16 + fq * 4 + r;
      const float lai = la_s[i];
      #pragma unroll
      for (int nt = 0; nt < 8; ++nt) {
        const int j = nt * 16 + fr;
        float v = 0.f;
        if (j <= i) v = acc_g[mt][nt][r] * expf(lai - la_s[j]) * dt_s[j];
        bm[i * 136 + j] = f2bf(v);
      }
    }

  // Y_inter = C @ S_start^T  (K = n); S frags direct from global
  const size_t slot = (size_t)blockIdx.x * 8192;
  f32x4 acc_y[2][4];
  #pragma unroll
  for (int mt = 0; mt < 2; ++mt)
    #pragma unroll
    for (int pt = 0; pt < 4; ++pt) acc_y[mt][pt] = splat4(0.f);
  #pragma unroll
  for (int k0 = 0; k0 < 128; k0 += 32) {
    bf16x8 af[2], bs[4];
    #pragma unroll
    for (int mt = 0; mt < 2; ++mt)
      af[mt] = *(const bf16x8*)(Cbase + (size_t)(wm + mt * 16 + fr) * 2304 + k0);
    #pragma unroll
    for (int pt = 0; pt < 4; ++pt)
      bs[pt] = *(const bf16x8*)(Sg + slot + (size_t)(pt * 16 + fr) * 128 + fq * 8 + k0);
    #pragma unroll
    for (int mt = 0; mt < 2; ++mt)
      #pragma unroll
      for (int pt = 0; pt < 4; ++pt)
        acc_y[mt][pt] = __builtin_amdgcn_mfma_f32_16x16x32_bf16(af[mt], bs[pt], acc_y[mt][pt], 0, 0, 0);
  }
  // scale inter-chunk term by exp(la_i)
  #pragma unroll
  for (int mt = 0; mt < 2; ++mt)
    #pragma unroll
    for (int r = 0; r < 4; ++r) {
      const float el = expf(la_s[wm + mt * 16 + fq * 4 + r]);
      #pragma unroll
      for (int pt = 0; pt < 4; ++pt) acc_y[mt][pt][r] *= el;
    }
  __syncthreads();

  // y += M @ X  (K = j); M rows are wave-private
  #pragma unroll
  for (int k0 = 0; k0 < 128; k0 += 32) {
    bf16x8 am[2], bx[4];
    #pragma unroll
    for (int mt = 0; mt < 2; ++mt)
      am[mt] = *(const bf16x8*)(bm + (wm + mt * 16 + fr) * 136 + fq * 8 + k0);
    #pragma unroll
    for (int pt = 0; pt < 4; ++pt)
      bx[pt] = *(const bf16x8*)(xT + (pt * 16 + fr) * 136 + fq * 8 + k0);
    #pragma unroll
    for (int mt = 0; mt < 2; ++mt)
      #pragma unroll
      for (int pt = 0; pt < 4; ++pt)
        acc_y[mt][pt] = __builtin_amdgcn_mfma_f32_16x16x32_bf16(am[mt], bx[pt], acc_y[mt][pt], 0, 0, 0);
  }

  // fused gate epilogue: out = (y + D*x) * silu(z), in place over convo x-cols
  const float D = D_param[h];
  #pragma unroll
  for (int mt = 0; mt < 2; ++mt)
    #pragma unroll
    for (int r = 0; r < 4; ++r) {
      const int i = wm + mt * 16 + fq * 4 + r;
      const size_t grow = r0 + i;
      #pragma unroll
      for (int pt = 0; pt < 4; ++pt) {
        const int p = pt * 16 + fr;
        const float x = bf2f(xT[p * 136 + i]);
        const float z = bf2f(zx[grow * 4480 + h * 64 + p]);
        const float sg = z / (1.0f + expf(-z));
        convo[grow * 2304 + h * 64 + p] = f2bf((acc_y[mt][pt][r] + D * x) * sg);
      }
    }
}

// ---------------- SwiGLU activation: g = silu(g) * u, in place ----------------
__global__ __launch_bounds__(256) void act_kernel(
    unsigned short* __restrict__ g, const unsigned short* __restrict__ u)
{
  size_t i4 = ((size_t)blockIdx.x * 256 + threadIdx.x) * 4;
  if (i4 >= (size_t)8192 * 4096) return;
  ushort4 gv = *(ushort4*)(g + i4);
  ushort4 uv = *(const ushort4*)(u + i4);
  float x, s, o[4];
  x = bf2f(gv.x); s = x / (1.0f + expf(-x)); o[0] = s * bf2f(uv.x);
  x = bf2f(gv.y); s = x / (1.0f + expf(-x)); o[1] = s * bf2f(uv.y);
  x = bf2f(gv.z); s = x / (1.0f + expf(-x)); o[2] = s * bf2f(uv.z);
  x = bf2f(gv.w); s = x / (1.0f + expf(-x)); o[3] = s * bf2f(uv.w);
  *(ushort4*)(g + i4) = make_ushort4(f2bf(o[0]), f2bf(o[1]), f2bf(o[2]), f2bf(o[3]));
}

// ---------------- workspace arena (bytes) ----------------
static constexpr size_t OFF_RES1 = 0;            // fp32 8192x1024 (live until rmsnorm2)
static constexpr size_t OFF_H1   = 33554432;     // bf16 8192x1024 (h1; then Sg 33.55MB; then mamba_out)
static constexpr size_t OFF_W    = 83886080;     // bf16 weight staging (also Pend during scan)
static constexpr size_t OFF_ZX   = 93061120;     // bf16 8192x4480   (zxbcdt, then g_out)
static constexpr size_t OFF_CONV = 166461440;    // bf16 8192x2304   (in_proj W staging -> conv_out -> gated y -> h2)
static constexpr size_t OFF_DTDA = 204210176;    // float2 8192x32 (dt, dA) = 2 MB
static constexpr size_t OFF_U    = 0;            // bf16 8192x4096   (overlaps dead res1/h1/Sg)

extern "C" void kernel_launch(void* const* d_in, const int* in_sizes, int n_in,
                              void* d_out, int out_size, void* d_ws, size_t ws_size,
                              hipStream_t stream) {
  const float* hid      = (const float*)d_in[0];
  const float* resid    = (const float*)d_in[1];
  const float* ssm_w    = (const float*)d_in[2];
  const float* mlp_w    = (const float*)d_in[3];
  const float* in_proj  = (const float*)d_in[4];
  const float* conv_w   = (const float*)d_in[5];
  const float* conv_b   = (const float*)d_in[6];
  const float* dt_bias  = (const float*)d_in[7];
  const float* A_log    = (const float*)d_in[8];
  const float* D_param  = (const float*)d_in[9];
  const float* out_proj = (const float*)d_in[10];
  const float* gate_w   = (const float*)d_in[11];
  const float* up_w     = (const float*)d_in[12];
  const float* down_w   = (const float*)d_in[13];
  float* out = (float*)d_out;                       // fp32 output: [h | res]
  char* ws = (char*)d_ws;

  float*          res1  = (float*)(ws + OFF_RES1);
  unsigned short* h1    = (unsigned short*)(ws + OFF_H1);   // h1 / Sg / mamba_out
  unsigned short* Wb    = (unsigned short*)(ws + OFF_W);
  unsigned short* zx    = (unsigned short*)(ws + OFF_ZX);
  unsigned short* convo = (unsigned short*)(ws + OFF_CONV);
  float2*         dtda  = (float2*)(ws + OFF_DTDA);
  unsigned short* ub    = (unsigned short*)(ws + OFF_U);
  unsigned short* Sg    = h1;                               // 2048 tiles x 8192 bf16 = 33.55 MB
  float*          Pend  = (float*)(ws + OFF_W);             // 8KB, Wb dead during scan
  unsigned short* WinP  = convo;                            // in_proj weights (4608x1024), convo dead here

  rmsnorm1_kernel<<<8192, 256, 0, stream>>>(hid, resid, ssm_w, res1, h1);
  // in_proj weights padded to 4608 rows (18 x 256) staged in dead convo region
  cast_w<<<4608, 256, 0, stream>>>(in_proj, WinP, 4384, 1024, 4608);
  gemm256<unsigned short, 256><<<dim3(18, 32), 512, 0, stream>>>(h1, WinP, zx, 1024, 1024, 4480, 4480);
  conv_dt_kernel<<<74752, 256, 0, stream>>>(zx, conv_w, conv_b, dt_bias, A_log,
                                            convo, dtda);
  // chunked scan, matmul form: local states -> sequential combine -> outputs+gate
  chunk_state_kernel<<<2048, 256, 0, stream>>>(convo, dtda, A_log, Sg, Pend);
  chunk_combine_kernel<<<512, 256, 0, stream>>>(Sg, Pend);
  chunk_output_kernel<<<2048, 256, 0, stream>>>(convo, dtda, A_log, Sg, zx, D_param);
  cast_w<<<2048, 256, 0, stream>>>(out_proj, Wb, 1024, 2048, 1024);
  gemm256<unsigned short, 128><<<dim3(8, 32), 512, 0, stream>>>(convo, Wb, h1, 2048, 2304, 1024, 1024);
  rmsnorm2_kernel<<<8192, 256, 0, stream>>>(h1, res1, mlp_w, out + 8388608, convo);
  cast_w<<<4096, 256, 0, stream>>>(gate_w, Wb, 4096, 1024, 4096);
  gemm256<unsigned short, 256><<<dim3(16, 32), 512, 0, stream>>>(convo, Wb, zx, 1024, 1024, 4096, 4096);
  cast_w<<<4096, 256, 0, stream>>>(up_w, Wb, 4096, 1024, 4096);
  gemm256<unsigned short, 256><<<dim3(16, 32), 512, 0, stream>>>(convo, Wb, ub, 1024, 1024, 4096, 4096);
  act_kernel<<<32768, 256, 0, stream>>>(zx, ub);
  cast_w<<<4096, 256, 0, stream>>>(down_w, Wb, 1024, 4096, 1024);
  gemm256<float, 128><<<dim3(8, 32), 512, 0, stream>>>(zx, Wb, out, 4096, 4096, 1024, 1024);
}

// Round 6
// 833.101 us; speedup vs baseline: 1.3160x; 1.0533x over previous
//
#include <hip/hip_runtime.h>

typedef __bf16 bf16x8 __attribute__((ext_vector_type(8)));
typedef float  f32x4  __attribute__((ext_vector_type(4)));

#define GLOAD_LDS16(gp, lp) \
  __builtin_amdgcn_global_load_lds((const __attribute__((address_space(1))) void*)(gp), \
                                   (__attribute__((address_space(3))) void*)(lp), 16, 0, 0)

__device__ __forceinline__ unsigned short f2bf(float f) {
  unsigned u = __float_as_uint(f);
  u += 0x7fffu + ((u >> 16) & 1u);
  return (unsigned short)(u >> 16);
}
__device__ __forceinline__ float bf2f(unsigned short h) {
  return __uint_as_float(((unsigned)h) << 16);
}
__device__ __forceinline__ f32x4 splat4(float v) { f32x4 r = {v, v, v, v}; return r; }

// unpack 4 consecutive bf16 (packed in two uints) -> f32x4
__device__ __forceinline__ f32x4 up4(unsigned lo, unsigned hi) {
  f32x4 r;
  r[0] = __uint_as_float(lo << 16); r[1] = __uint_as_float(lo & 0xffff0000u);
  r[2] = __uint_as_float(hi << 16); r[3] = __uint_as_float(hi & 0xffff0000u);
  return r;
}
__device__ __forceinline__ unsigned pk2(float a, float b) {
  return (unsigned)f2bf(a) | ((unsigned)f2bf(b) << 16);
}

__device__ __forceinline__ void store_out(unsigned short* C, size_t idx, float v) {
  C[idx] = f2bf(v);
}
__device__ __forceinline__ void store_out(float* C, size_t idx, float v) {
  C[idx] = v;
}

// ---------------- RMSNorm (prenorm) #1 ----------------
__global__ __launch_bounds__(256) void rmsnorm1_kernel(
    const float* __restrict__ hid, const float* __restrict__ resin,
    const float* __restrict__ w, float* __restrict__ resout,
    unsigned short* __restrict__ hout)
{
  const int row = blockIdx.x, t = threadIdx.x;
  const size_t base = (size_t)row * 1024;
  float4 h = ((const float4*)(hid + base))[t];
  float4 r = ((const float4*)(resin + base))[t];
  float4 s; s.x = h.x + r.x; s.y = h.y + r.y; s.z = h.z + r.z; s.w = h.w + r.w;
  float ss = s.x*s.x + s.y*s.y + s.z*s.z + s.w*s.w;
  #pragma unroll
  for (int off = 32; off; off >>= 1) ss += __shfl_down(ss, off, 64);
  __shared__ float red[4];
  if ((t & 63) == 0) red[t >> 6] = ss;
  __syncthreads();
  float tot = red[0] + red[1] + red[2] + red[3];
  float sc = rsqrtf(tot * (1.0f/1024.0f) + 1e-5f);
  ((float4*)(resout + base))[t] = s;
  float4 wv = ((const float4*)w)[t];
  ushort4 o = make_ushort4(f2bf(s.x*sc*wv.x), f2bf(s.y*sc*wv.y),
                           f2bf(s.z*sc*wv.z), f2bf(s.w*sc*wv.w));
  ((ushort4*)(hout + base))[t] = o;
}

// ---------------- RMSNorm (prenorm) #2 ----------------
__global__ __launch_bounds__(256) void rmsnorm2_kernel(
    const unsigned short* __restrict__ mo, const float* __restrict__ res1,
    const float* __restrict__ w, float* __restrict__ res_out,
    unsigned short* __restrict__ h2)
{
  const int row = blockIdx.x, t = threadIdx.x;
  const size_t base = (size_t)row * 1024;
  float4 r = ((const float4*)(res1 + base))[t];
  ushort4 m = ((const ushort4*)(mo + base))[t];
  float4 s; s.x = r.x + bf2f(m.x); s.y = r.y + bf2f(m.y);
            s.z = r.z + bf2f(m.z); s.w = r.w + bf2f(m.w);
  float ss = s.x*s.x + s.y*s.y + s.z*s.z + s.w*s.w;
  #pragma unroll
  for (int off = 32; off; off >>= 1) ss += __shfl_down(ss, off, 64);
  __shared__ float red[4];
  if ((t & 63) == 0) red[t >> 6] = ss;
  __syncthreads();
  float tot = red[0] + red[1] + red[2] + red[3];
  float sc = rsqrtf(tot * (1.0f/1024.0f) + 1e-5f);
  ((float4*)(res_out + base))[t] = s;
  float4 wv = ((const float4*)w)[t];
  ((ushort4*)(h2 + base))[t] = make_ushort4(f2bf(s.x*sc*wv.x), f2bf(s.y*sc*wv.y),
                                            f2bf(s.z*sc*wv.z), f2bf(s.w*sc*wv.w));
}

// ---------------- fp32 -> bf16 weight cast with row padding ----------------
__global__ __launch_bounds__(256) void cast_w(
    const float* __restrict__ src, unsigned short* __restrict__ dst,
    int rows, int cols, int prows)
{
  size_t i4 = ((size_t)blockIdx.x * 256 + threadIdx.x) * 4;
  size_t total = (size_t)prows * cols;
  if (i4 >= total) return;
  int r = (int)(i4 / cols);
  ushort4 o;
  if (r < rows) {
    float4 v = *(const float4*)(src + i4);
    o = make_ushort4(f2bf(v.x), f2bf(v.y), f2bf(v.z), f2bf(v.w));
  } else {
    o = make_ushort4(0, 0, 0, 0);
  }
  *(ushort4*)(dst + i4) = o;
}

// ================= bf16 GEMM (NT), 256 x TN tile, BK=64, 1-barrier/tile =====
// A: M x K row-major (stride lda). W: N x K row-major packed. Grid (Npad/TN, M/256),
// 512 threads = 8 waves (2M x 4N), per-wave C = 128 x TN/4.
// Per K-tile: vmcnt(0) [stages issued a full tile ago -> latency covered] ->
// ONE s_barrier [all stages landed; all waves done with other buffer] ->
// issue next tile's stages -> straight-line quadrant ds_reads + MFMAs with NO
// manual lgkm fences (compiler inserts fine-grained counted waits; waves slip
// against each other so LDS and matrix pipes overlap across the 2 waves/SIMD).
// Swizzle: 16B-granule g ^= (row&7); linear gload_lds dest, inverse swizzle on
// per-lane global source; ds_read applies the same XOR -> conflict-free.
template <typename OutT, int TN>
__global__ __launch_bounds__(512) void gemm256(
    const unsigned short* __restrict__ A, const unsigned short* __restrict__ W,
    OutT* __restrict__ C, int K, int lda, int ldc, int Nst)
{
  constexpr int NH = TN / 128;          // B half-tiles (2 or 1)
  constexpr int WN = TN / 4;            // per-wave N width (64 or 32)
  constexpr int QN = TN / 128;          // N-frags per quadrant (2 or 1)
  __shared__ __align__(16) unsigned short As[2][2][8192];
  __shared__ __align__(16) unsigned short Bs[2][NH][8192];

  // XCD-bijective block swizzle (m204)
  const int gx = gridDim.x, nwg = gx * (int)gridDim.y;
  int lin = blockIdx.y * gx + blockIdx.x;
  {
    const int q = nwg >> 3, r = nwg & 7, xcd = lin & 7, lo = lin >> 3;
    lin = (xcd < r ? xcd * (q + 1) : r * (q + 1) + (xcd - r) * q) + lo;
  }
  const int n0 = (lin % gx) * TN, m0 = (lin / gx) << 8;

  const int t = threadIdx.x, lane = t & 63, w = t >> 6;
  const int wr = w >> 2, wc = w & 3;
  const int fr = lane & 15, fq = lane >> 4;

  f32x4 acc[8][2 * QN];
  #pragma unroll
  for (int i = 0; i < 8; ++i)
    #pragma unroll
    for (int j = 0; j < 2 * QN; ++j) acc[i][j] = splat4(0.f);

  auto stA = [&](int buf, int h, int kc) {
    #pragma unroll
    for (int r2 = 0; r2 < 2; ++r2) {
      const int R = r2 * 64 + (t >> 3);
      const unsigned short* g =
          A + (size_t)(m0 + h * 128 + R) * lda + kc + (((t & 7) ^ (R & 7)) << 3);
      GLOAD_LDS16(g, &As[buf][h][r2 * 4096 + t * 8]);
    }
  };
  auto stB = [&](int buf, int h, int kc) {
    #pragma unroll
    for (int r2 = 0; r2 < 2; ++r2) {
      const int R = r2 * 64 + (t >> 3);
      const unsigned short* g =
          W + (size_t)(n0 + h * 128 + R) * (size_t)K + kc + (((t & 7) ^ (R & 7)) << 3);
      GLOAD_LDS16(g, &Bs[buf][h][r2 * 4096 + t * 8]);
    }
  };

  bf16x8 af[4][2], bqX[QN][2], bqY[QN][2];

#define G256_LDA(MH)                                                           \
  _Pragma("unroll") for (int mi = 0; mi < 4; ++mi)                             \
    _Pragma("unroll") for (int ks = 0; ks < 2; ++ks) {                         \
      const int R = (MH) * 64 + mi * 16 + fr;                                  \
      af[mi][ks] = *(const bf16x8*)(&As[cb][wr][R * 64 +                       \
                        ((((ks << 2) + fq) ^ (R & 7)) << 3)]);                 \
    }

#define G256_LDB(BQ, NHH)                                                      \
  _Pragma("unroll") for (int ni = 0; ni < QN; ++ni)                            \
    _Pragma("unroll") for (int ks = 0; ks < 2; ++ks) {                         \
      const int half = (NH == 2) ? (wc >> 1) : 0;                              \
      const int R = (NH == 2) ? ((wc & 1) * 64 + (NHH) * 32 + ni * 16 + fr)    \
                              : (wc * 32 + (NHH) * 16 + fr);                   \
      BQ[ni][ks] = *(const bf16x8*)(&Bs[cb][half][R * 64 +                     \
                        ((((ks << 2) + fq) ^ (R & 7)) << 3)]);                 \
    }

#define G256_MQ(BQ, MH, NHH)                                                   \
  __builtin_amdgcn_s_setprio(1);                                               \
  _Pragma("unroll") for (int ks = 0; ks < 2; ++ks)                             \
    _Pragma("unroll") for (int mi = 0; mi < 4; ++mi)                           \
      _Pragma("unroll") for (int ni = 0; ni < QN; ++ni)                        \
        acc[(MH) * 4 + mi][(NHH) * QN + ni] =                                  \
            __builtin_amdgcn_mfma_f32_16x16x32_bf16(                           \
                af[mi][ks], BQ[ni][ks],                                        \
                acc[(MH) * 4 + mi][(NHH) * QN + ni], 0, 0, 0);                 \
  __builtin_amdgcn_s_setprio(0);

  const int NKT = K >> 6;
  // prologue: stage K-tile 0 into buf 0
  stA(0, 0, 0);
  stA(0, 1, 0);
  stB(0, 0, 0);
  if (NH > 1) stB(0, 1, 0);

  for (int kt = 0; kt < NKT; ++kt) {
    const int cb = kt & 1, nb = cb ^ 1;
    const int kc1 = (kt + 1) << 6;
    const bool p1 = (kt + 1 < NKT);
    // tile kt's stages were issued one full tile-body ago -> latency covered
    asm volatile("s_waitcnt vmcnt(0)" ::: "memory");
    __builtin_amdgcn_s_barrier();   // stages landed everywhere; buf nb free
    if (p1) {
      stA(nb, 0, kc1);
      stA(nb, 1, kc1);
      stB(nb, 0, kc1);
      if (NH > 1) stB(nb, 1, kc1);
    }
    // straight-line quadrants; compiler schedules ds_reads vs MFMAs
    G256_LDA(0)
    G256_LDB(bqX, 0)
    G256_MQ(bqX, 0, 0)
    G256_LDB(bqY, 1)
    G256_MQ(bqY, 0, 1)
    G256_LDA(1)
    G256_MQ(bqY, 1, 1)
    G256_LDB(bqX, 0)
    G256_MQ(bqX, 1, 0)
  }
#undef G256_LDA
#undef G256_LDB
#undef G256_MQ

  #pragma unroll
  for (int mi = 0; mi < 8; ++mi)
    #pragma unroll
    for (int ci = 0; ci < 2 * QN; ++ci)
      #pragma unroll
      for (int rr = 0; rr < 4; ++rr) {
        const int gm = m0 + wr * 128 + mi * 16 + fq * 4 + rr;
        const int gn = n0 + wc * WN + ci * 16 + fr;
        if (gn < Nst) store_out(C, (size_t)gm * ldc + gn, acc[mi][ci][rr]);
      }
}

// ---------------- causal depthwise conv (K=4) + silu, dt precompute ----------------
__global__ __launch_bounds__(256) void conv_dt_kernel(
    const unsigned short* __restrict__ zx, const float* __restrict__ conv_w,
    const float* __restrict__ conv_b, const float* __restrict__ dt_bias,
    const float* __restrict__ A_log, unsigned short* __restrict__ conv_out,
    float2* __restrict__ dtda)
{
  size_t idx = (size_t)blockIdx.x * 256 + threadIdx.x;
  if (idx >= (size_t)8192 * 2336) return;
  int c = (int)(idx % 2336);
  int row = (int)(idx / 2336);
  int l = row & 4095;
  if (c < 2304) {
    float acc = conv_b[c];
    const float* wp = conv_w + c * 4;
    #pragma unroll
    for (int j = 0; j < 4; j++) {
      int ls = l - 3 + j;
      if (ls >= 0) acc += bf2f(zx[(size_t)(row - 3 + j) * 4480 + 2048 + c]) * wp[j];
    }
    float s = acc / (1.0f + expf(-acc));
    conv_out[(size_t)row * 2304 + c] = f2bf(s);
  } else {
    int h = c - 2304;
    float draw = bf2f(zx[(size_t)row * 4480 + 4352 + h]) + dt_bias[h];
    float sp = (draw > 20.0f) ? draw : log1pf(expf(draw));
    float Ah = -expf(A_log[h]);
    dtda[(size_t)row * 32 + h] = make_float2(sp, expf(sp * Ah));
  }
}

// ============ chunked selective scan via MFMA (state-space-dual form) ============
// Q=128 chunk, 32 chunks/seq. Tile id: c = bid&31, h = (bid>>5)&31, b = bid>>10.

// Kernel A: per-chunk local end state S_end = (X .* w)^T @ B, w_j = exp(laQ-la_j)*dt_j.
__global__ __launch_bounds__(256) void chunk_state_kernel(
    const unsigned short* __restrict__ convo, const float2* __restrict__ dtda,
    const float* __restrict__ A_log, unsigned short* __restrict__ Sg,
    float* __restrict__ Pend)
{
  __shared__ __align__(16) unsigned short bT[128 * 136];  // B^T: [n][j]
  __shared__ __align__(16) unsigned short xT[64 * 136];   // weighted X^T: [p][j]
  __shared__ float wsh[128];
  const int t = threadIdx.x, lane = t & 63, wv = t >> 6;
  const int c = blockIdx.x & 31, h = (blockIdx.x >> 5) & 31, b = (int)(blockIdx.x >> 10);
  const size_t r0 = (size_t)b * 4096 + (size_t)c * 128;

  if (wv == 0) {
    const float A = -expf(A_log[h]);
    const float s0 = dtda[(r0 + 2 * lane) * 32 + h].x;
    const float s1 = dtda[(r0 + 2 * lane + 1) * 32 + h].x;
    const float v1 = s1 * A;
    float ps = s0 * A + v1;                         // pair sum of log-decay
    #pragma unroll
    for (int off = 1; off < 64; off <<= 1) {
      float n = __shfl_up(ps, off, 64);
      if (lane >= off) ps += n;
    }
    const float laQ = __shfl(ps, 63, 64);
    wsh[2 * lane]     = expf(laQ - (ps - v1)) * s0;  // la[2l] = ps - v1
    wsh[2 * lane + 1] = expf(laQ - ps) * s1;         // la[2l+1] = ps
    if (lane == 63) Pend[blockIdx.x] = expf(laQ);
  }
  __syncthreads();

  // stage weighted X^T: xT[p][j] = X[j][p] * w[j]
  {
    int j = t >> 3;
    const int p0 = (t & 7) << 3;
    #pragma unroll
    for (int it = 0; it < 4; ++it, j += 32) {
      const uint4 v = *(const uint4*)(convo + (r0 + j) * 2304 + h * 64 + p0);
      const float w = wsh[j];
      const unsigned arr[4] = {v.x, v.y, v.z, v.w};
      #pragma unroll
      for (int e = 0; e < 8; ++e) {
        const unsigned short raw = (unsigned short)(arr[e >> 1] >> ((e & 1) * 16));
        xT[(p0 + e) * 136 + j] = f2bf(bf2f(raw) * w);
      }
    }
  }
  // stage B^T: bT[n][j] = B[j][n]
  {
    int j = t >> 4;
    const int n0 = (t & 15) << 3;
    #pragma unroll
    for (int it = 0; it < 8; ++it, j += 16) {
      const uint4 v = *(const uint4*)(convo + (r0 + j) * 2304 + 2048 + n0);
      const unsigned arr[4] = {v.x, v.y, v.z, v.w};
      #pragma unroll
      for (int e = 0; e < 8; ++e)
        bT[(n0 + e) * 136 + j] = (unsigned short)(arr[e >> 1] >> ((e & 1) * 16));
    }
  }
  __syncthreads();

  const int fr = lane & 15, fq = lane >> 4;
  const int wn = wv << 5;                 // wave owns n columns [wn, wn+32)
  f32x4 acc[4][2];
  #pragma unroll
  for (int i = 0; i < 4; ++i)
    #pragma unroll
    for (int j = 0; j < 2; ++j) acc[i][j] = splat4(0.f);

  #pragma unroll
  for (int k0 = 0; k0 < 128; k0 += 32) {
    bf16x8 af[4], bf[2];
    #pragma unroll
    for (int i = 0; i < 4; ++i)
      af[i] = *(const bf16x8*)(xT + (i * 16 + fr) * 136 + fq * 8 + k0);
    #pragma unroll
    for (int j = 0; j < 2; ++j)
      bf[j] = *(const bf16x8*)(bT + (wn + j * 16 + fr) * 136 + fq * 8 + k0);
    #pragma unroll
    for (int i = 0; i < 4; ++i)
      #pragma unroll
      for (int j = 0; j < 2; ++j)
        acc[i][j] = __builtin_amdgcn_mfma_f32_16x16x32_bf16(af[i], bf[j], acc[i][j], 0, 0, 0);
  }

  const size_t slot = (size_t)blockIdx.x * 8192;
  #pragma unroll
  for (int i = 0; i < 4; ++i)
    #pragma unroll
    for (int j = 0; j < 2; ++j)
      #pragma unroll
      for (int r = 0; r < 4; ++r)
        Sg[slot + (size_t)(i * 16 + fq * 4 + r) * 128 + wn + j * 16 + fr] = f2bf(acc[i][j][r]);
}

// Kernel combine: sequential over 32 chunks; in-place Send -> Sstart. Elementwise.
__global__ __launch_bounds__(256) void chunk_combine_kernel(
    unsigned short* __restrict__ S, const float* __restrict__ Pend)
{
  const int t = threadIdx.x;
  const int sl = blockIdx.x & 7, bh = blockIdx.x >> 3;
  const size_t e = (size_t)sl * 1024 + (size_t)t * 4;
  f32x4 run = splat4(0.f);
  for (int c = 0; c < 32; ++c) {
    const size_t addr = (size_t)(bh * 32 + c) * 8192 + e;
    const uint2 a = *(const uint2*)(S + addr);
    const float P = Pend[bh * 32 + c];
    *(uint2*)(S + addr) = make_uint2(pk2(run[0], run[1]), pk2(run[2], run[3]));
    const f32x4 av = up4(a.x, a.y);
    run = av + splat4(P) * run;
  }
}

// Kernel B: y = (G .* decay-mask) @ X + diag(exp(la_i)) * (C @ S_start^T),
// then fused gate: out = (y + D*x) * silu(z), written IN PLACE over convo's x cols.
__global__ __launch_bounds__(256, 2) void chunk_output_kernel(
    unsigned short* __restrict__ convo, const float2* __restrict__ dtda,
    const float* __restrict__ A_log, const unsigned short* __restrict__ Sg,
    const unsigned short* __restrict__ zx, const float* __restrict__ D_param)
{
  __shared__ __align__(16) unsigned short bm[128 * 136]; // B tile [j][n], then M [i][j]
  __shared__ __align__(16) unsigned short xT[64 * 136];  // X^T [p][j]
  __shared__ float la_s[128];
  __shared__ float dt_s[128];
  const int t = threadIdx.x, lane = t & 63, wv = t >> 6;
  const int c = blockIdx.x & 31, h = (blockIdx.x >> 5) & 31, b = (int)(blockIdx.x >> 10);
  const size_t r0 = (size_t)b * 4096 + (size_t)c * 128;

  if (wv == 0) {
    const float A = -expf(A_log[h]);
    const float s0 = dtda[(r0 + 2 * lane) * 32 + h].x;
    const float s1 = dtda[(r0 + 2 * lane + 1) * 32 + h].x;
    const float v1 = s1 * A;
    float ps = s0 * A + v1;
    #pragma unroll
    for (int off = 1; off < 64; off <<= 1) {
      float n = __shfl_up(ps, off, 64);
      if (lane >= off) ps += n;
    }
    la_s[2 * lane] = ps - v1;
    la_s[2 * lane + 1] = ps;
    dt_s[2 * lane] = s0;
    dt_s[2 * lane + 1] = s1;
  }

  // stage B rows direct (row-major, K=n contiguous)
  {
    int j = t >> 4;
    const int n0 = (t & 15) << 3;
    #pragma unroll
    for (int it = 0; it < 8; ++it, j += 16)
      *(uint4*)(bm + j * 136 + n0) = *(const uint4*)(convo + (r0 + j) * 2304 + 2048 + n0);
  }
  // stage X^T (unweighted)
  {
    int j = t >> 3;
    const int p0 = (t & 7) << 3;
    #pragma unroll
    for (int it = 0; it < 4; ++it, j += 32) {
      const uint4 v = *(const uint4*)(convo + (r0 + j) * 2304 + h * 64 + p0);
      const unsigned arr[4] = {v.x, v.y, v.z, v.w};
      #pragma unroll
      for (int e = 0; e < 8; ++e)
        xT[(p0 + e) * 136 + j] = (unsigned short)(arr[e >> 1] >> ((e & 1) * 16));
    }
  }
  __syncthreads();

  const int fr = lane & 15, fq = lane >> 4;
  const int wm = wv << 5;                 // wave owns output rows [wm, wm+32)
  const unsigned short* Cbase = convo + r0 * 2304 + 2176 + fq * 8;

  // G = C @ B^T  (K = n).  C A-frags straight from global (L1/L2 resident).
  f32x4 acc_g[2][8];
  #pragma unroll
  for (int mt = 0; mt < 2; ++mt)
    #pragma unroll
    for (int nt = 0; nt < 8; ++nt) acc_g[mt][nt] = splat4(0.f);
  #pragma unroll
  for (int k0 = 0; k0 < 128; k0 += 32) {
    bf16x8 af[2], bg[8];
    #pragma unroll
    for (int mt = 0; mt < 2; ++mt)
      af[mt] = *(const bf16x8*)(Cbase + (size_t)(wm + mt * 16 + fr) * 2304 + k0);
    #pragma unroll
    for (int nt = 0; nt < 8; ++nt)
      bg[nt] = *(const bf16x8*)(bm + (nt * 16 + fr) * 136 + fq * 8 + k0);
    #pragma unroll
    for (int mt = 0; mt < 2; ++mt)
      #pragma unroll
      for (int nt = 0; nt < 8; ++nt)
        acc_g[mt][nt] = __builtin_amdgcn_mfma_f32_16x16x32_bf16(af[mt], bg[nt], acc_g[mt][nt], 0, 0, 0);
  }
  __syncthreads();  // all waves done reading B before M overwrites bm

  // decay-mask: M[i][j] = G[i][j]*exp(la_i-la_j)*dt_j for j<=i else 0  (bf16, over bm)
  #pragma unroll
  for (int mt = 0; mt < 2; ++mt)
    #pragma unroll
    for (int r = 0; r < 4; ++r) {
      const int i = wm + mt * 16 + fq * 4 + r;
      const float lai = la_s[i];
      #pragma unroll
      for (int nt = 0; nt < 8; ++nt) {
        const int j = nt * 16 + fr;
        float v = 0.f;
        if (j <= i) v = acc_g[mt][nt][r] * expf(lai - la_s[j]) * dt_s[j];
        bm[i * 136 + j] = f2bf(v);
      }
    }

  // Y_inter = C @ S_start^T  (K = n); S frags direct from global
  const size_t slot = (size_t)blockIdx.x * 8192;
  f32x4 acc_y[2][4];
  #pragma unroll
  for (int mt = 0; mt < 2; ++mt)
    #pragma unroll
    for (int pt = 0; pt < 4; ++pt) acc_y[mt][pt] = splat4(0.f);
  #pragma unroll
  for (int k0 = 0; k0 < 128; k0 += 32) {
    bf16x8 af[2], bs[4];
    #pragma unroll
    for (int mt = 0; mt < 2; ++mt)
      af[mt] = *(const bf16x8*)(Cbase + (size_t)(wm + mt * 16 + fr) * 2304 + k0);
    #pragma unroll
    for (int pt = 0; pt < 4; ++pt)
      bs[pt] = *(const bf16x8*)(Sg + slot + (size_t)(pt * 16 + fr) * 128 + fq * 8 + k0);
    #pragma unroll
    for (int mt = 0; mt < 2; ++mt)
      #pragma unroll
      for (int pt = 0; pt < 4; ++pt)
        acc_y[mt][pt] = __builtin_amdgcn_mfma_f32_16x16x32_bf16(af[mt], bs[pt], acc_y[mt][pt], 0, 0, 0);
  }
  // scale inter-chunk term by exp(la_i)
  #pragma unroll
  for (int mt = 0; mt < 2; ++mt)
    #pragma unroll
    for (int r = 0; r < 4; ++r) {
      const float el = expf(la_s[wm + mt * 16 + fq * 4 + r]);
      #pragma unroll
      for (int pt = 0; pt < 4; ++pt) acc_y[mt][pt][r] *= el;
    }
  __syncthreads();

  // y += M @ X  (K = j); M rows are wave-private
  #pragma unroll
  for (int k0 = 0; k0 < 128; k0 += 32) {
    bf16x8 am[2], bx[4];
    #pragma unroll
    for (int mt = 0; mt < 2; ++mt)
      am[mt] = *(const bf16x8*)(bm + (wm + mt * 16 + fr) * 136 + fq * 8 + k0);
    #pragma unroll
    for (int pt = 0; pt < 4; ++pt)
      bx[pt] = *(const bf16x8*)(xT + (pt * 16 + fr) * 136 + fq * 8 + k0);
    #pragma unroll
    for (int mt = 0; mt < 2; ++mt)
      #pragma unroll
      for (int pt = 0; pt < 4; ++pt)
        acc_y[mt][pt] = __builtin_amdgcn_mfma_f32_16x16x32_bf16(am[mt], bx[pt], acc_y[mt][pt], 0, 0, 0);
  }

  // fused gate epilogue: out = (y + D*x) * silu(z), in place over convo x-cols
  const float D = D_param[h];
  #pragma unroll
  for (int mt = 0; mt < 2; ++mt)
    #pragma unroll
    for (int r = 0; r < 4; ++r) {
      const int i = wm + mt * 16 + fq * 4 + r;
      const size_t grow = r0 + i;
      #pragma unroll
      for (int pt = 0; pt < 4; ++pt) {
        const int p = pt * 16 + fr;
        const float x = bf2f(xT[p * 136 + i]);
        const float z = bf2f(zx[grow * 4480 + h * 64 + p]);
        const float sg = z / (1.0f + expf(-z));
        convo[grow * 2304 + h * 64 + p] = f2bf((acc_y[mt][pt][r] + D * x) * sg);
      }
    }
}

// ---------------- SwiGLU activation: g = silu(g) * u, in place ----------------
__global__ __launch_bounds__(256) void act_kernel(
    unsigned short* __restrict__ g, const unsigned short* __restrict__ u)
{
  size_t i4 = ((size_t)blockIdx.x * 256 + threadIdx.x) * 4;
  if (i4 >= (size_t)8192 * 4096) return;
  ushort4 gv = *(ushort4*)(g + i4);
  ushort4 uv = *(const ushort4*)(u + i4);
  float x, s, o[4];
  x = bf2f(gv.x); s = x / (1.0f + expf(-x)); o[0] = s * bf2f(uv.x);
  x = bf2f(gv.y); s = x / (1.0f + expf(-x)); o[1] = s * bf2f(uv.y);
  x = bf2f(gv.z); s = x / (1.0f + expf(-x)); o[2] = s * bf2f(uv.z);
  x = bf2f(gv.w); s = x / (1.0f + expf(-x)); o[3] = s * bf2f(uv.w);
  *(ushort4*)(g + i4) = make_ushort4(f2bf(o[0]), f2bf(o[1]), f2bf(o[2]), f2bf(o[3]));
}

// ---------------- workspace arena (bytes) ----------------
static constexpr size_t OFF_RES1 = 0;            // fp32 8192x1024 (live until rmsnorm2)
static constexpr size_t OFF_H1   = 33554432;     // bf16 8192x1024 (h1; then Sg 33.55MB; then mamba_out)
static constexpr size_t OFF_W    = 83886080;     // bf16 weight staging (also Pend during scan)
static constexpr size_t OFF_ZX   = 93061120;     // bf16 8192x4480   (zxbcdt, then g_out)
static constexpr size_t OFF_CONV = 166461440;    // bf16 8192x2304   (in_proj W staging -> conv_out -> gated y -> h2)
static constexpr size_t OFF_DTDA = 204210176;    // float2 8192x32 (dt, dA) = 2 MB
static constexpr size_t OFF_U    = 0;            // bf16 8192x4096   (overlaps dead res1/h1/Sg)

extern "C" void kernel_launch(void* const* d_in, const int* in_sizes, int n_in,
                              void* d_out, int out_size, void* d_ws, size_t ws_size,
                              hipStream_t stream) {
  const float* hid      = (const float*)d_in[0];
  const float* resid    = (const float*)d_in[1];
  const float* ssm_w    = (const float*)d_in[2];
  const float* mlp_w    = (const float*)d_in[3];
  const float* in_proj  = (const float*)d_in[4];
  const float* conv_w   = (const float*)d_in[5];
  const float* conv_b   = (const float*)d_in[6];
  const float* dt_bias  = (const float*)d_in[7];
  const float* A_log    = (const float*)d_in[8];
  const float* D_param  = (const float*)d_in[9];
  const float* out_proj = (const float*)d_in[10];
  const float* gate_w   = (const float*)d_in[11];
  const float* up_w     = (const float*)d_in[12];
  const float* down_w   = (const float*)d_in[13];
  float* out = (float*)d_out;                       // fp32 output: [h | res]
  char* ws = (char*)d_ws;

  float*          res1  = (float*)(ws + OFF_RES1);
  unsigned short* h1    = (unsigned short*)(ws + OFF_H1);   // h1 / Sg / mamba_out
  unsigned short* Wb    = (unsigned short*)(ws + OFF_W);
  unsigned short* zx    = (unsigned short*)(ws + OFF_ZX);
  unsigned short* convo = (unsigned short*)(ws + OFF_CONV);
  float2*         dtda  = (float2*)(ws + OFF_DTDA);
  unsigned short* ub    = (unsigned short*)(ws + OFF_U);
  unsigned short* Sg    = h1;                               // 2048 tiles x 8192 bf16 = 33.55 MB
  float*          Pend  = (float*)(ws + OFF_W);             // 8KB, Wb dead during scan
  unsigned short* WinP  = convo;                            // in_proj weights (4608x1024), convo dead here

  rmsnorm1_kernel<<<8192, 256, 0, stream>>>(hid, resid, ssm_w, res1, h1);
  // in_proj weights padded to 4608 rows (18 x 256) staged in dead convo region
  cast_w<<<4608, 256, 0, stream>>>(in_proj, WinP, 4384, 1024, 4608);
  gemm256<unsigned short, 256><<<dim3(18, 32), 512, 0, stream>>>(h1, WinP, zx, 1024, 1024, 4480, 4480);
  conv_dt_kernel<<<74752, 256, 0, stream>>>(zx, conv_w, conv_b, dt_bias, A_log,
                                            convo, dtda);
  // chunked scan, matmul form: local states -> sequential combine -> outputs+gate
  chunk_state_kernel<<<2048, 256, 0, stream>>>(convo, dtda, A_log, Sg, Pend);
  chunk_combine_kernel<<<512, 256, 0, stream>>>(Sg, Pend);
  chunk_output_kernel<<<2048, 256, 0, stream>>>(convo, dtda, A_log, Sg, zx, D_param);
  cast_w<<<2048, 256, 0, stream>>>(out_proj, Wb, 1024, 2048, 1024);
  gemm256<unsigned short, 128><<<dim3(8, 32), 512, 0, stream>>>(convo, Wb, h1, 2048, 2304, 1024, 1024);
  rmsnorm2_kernel<<<8192, 256, 0, stream>>>(h1, res1, mlp_w, out + 8388608, convo);
  cast_w<<<4096, 256, 0, stream>>>(gate_w, Wb, 4096, 1024, 4096);
  gemm256<unsigned short, 256><<<dim3(16, 32), 512, 0, stream>>>(convo, Wb, zx, 1024, 1024, 4096, 4096);
  cast_w<<<4096, 256, 0, stream>>>(up_w, Wb, 4096, 1024, 4096);
  gemm256<unsigned short, 256><<<dim3(16, 32), 512, 0, stream>>>(convo, Wb, ub, 1024, 1024, 4096, 4096);
  act_kernel<<<32768, 256, 0, stream>>>(zx, ub);
  cast_w<<<4096, 256, 0, stream>>>(down_w, Wb, 1024, 4096, 1024);
  gemm256<float, 128><<<dim3(8, 32), 512, 0, stream>>>(zx, Wb, out, 4096, 4096, 1024, 1024);
}